// Round 8
// baseline (4465.018 us; speedup 1.0000x reference)
//
#include <hip/hip_runtime.h>
#include <hip/hip_bf16.h>

#define BB 128
#define TT 128
#define HH 1024
#define NWG 256
#define NT 512

typedef __bf16 bf16x8 __attribute__((ext_vector_type(8)));
typedef __bf16 bf16x4 __attribute__((ext_vector_type(4)));
typedef float  f32x4v __attribute__((ext_vector_type(4)));

#define MFMA16(a,b,c) __builtin_amdgcn_mfma_f32_16x16x32_bf16(a,b,c,0,0,0)

__device__ inline float fsig(float x) {
  x = fminf(fmaxf(x, -30.f), 30.f);
  return 1.f / (1.f + __expf(-x));
}
__device__ inline float ftanh(float x) {
  x = fminf(fmaxf(x, -15.f), 15.f);
  float e = __expf(2.f * x);
  return (e - 1.f) / (e + 1.f);
}
// UC (LLC coherent-point) 8B store for cross-WG state: 4 consecutive bf16
__device__ inline void ucst64(__bf16* p, const f32x4v v) {
  union { unsigned long long u; __bf16 b[4]; } c;
#pragma unroll
  for (int j = 0; j < 4; ++j) c.b[j] = (__bf16)v[j];
  __hip_atomic_store((unsigned long long*)p, c.u, __ATOMIC_RELAXED, __HIP_MEMORY_SCOPE_AGENT);
}

// ---- DAG sync: aggregate monotone counters (r4 mechanism, unchanged). One
// counter per (role, batch-half, column-half), each on its own 64B line.
#define CPTR(role,bh,ch) (flags + (((role)*2+(bh))*2+(ch))*16)

#define SIGC(role,bh) do { \
  __syncthreads(); \
  if (tid == 0) \
    __hip_atomic_fetch_add(CPTR(role,bh,chg), 1, __ATOMIC_RELAXED, __HIP_MEMORY_SCOPE_AGENT); \
} while (0)

__device__ inline void cwait1(const int* C, int tgt, int tid) {
  if (tid < 64) {
    while (__hip_atomic_load(C, __ATOMIC_RELAXED, __HIP_MEMORY_SCOPE_AGENT) < tgt)
      __builtin_amdgcn_s_sleep(1);
    __builtin_amdgcn_fence(__ATOMIC_ACQUIRE, "agent");
  }
  __syncthreads();
  __builtin_amdgcn_sched_barrier(0);
}
__device__ inline void cwait2(const int* C0, const int* C1, int tgt, int tid, int lane) {
  if (tid < 64) {
    const int* P = (lane < 32) ? C0 : C1;
    while (__hip_atomic_load(P, __ATOMIC_RELAXED, __HIP_MEMORY_SCOPE_AGENT) < tgt)
      __builtin_amdgcn_s_sleep(1);
    __builtin_amdgcn_fence(__ATOMIC_ACQUIRE, "agent");
  }
  __syncthreads();
  __builtin_amdgcn_sched_barrier(0);
}

// ---- stage one 16x1024 f32 weight strip into LDS as swizzled bf16 (32KB), NT=512 ----
__device__ inline void stage_strip(char* dst, const float* src, int rstride, int tid) {
#pragma unroll
  for (int it = 0; it < 8; ++it) {
    int i = tid + it * NT;
    int rr = i >> 8;
    int c4 = i & 255;
    f32x4v v = *(const f32x4v*)(src + (size_t)rr * rstride + c4 * 4);
    bf16x4 o;
#pragma unroll
    for (int j = 0; j < 4; ++j) o[j] = (__bf16)v[j];
    *(bf16x4*)(dst + rr * 2048 + ((c4 * 8) ^ ((rr & 7) << 4))) = o;
  }
}

// ---- stage one 16x1024 bf16 strip into LDS swizzled (32KB), 256 threads ----
__device__ inline void stage_strip_b16(char* dst, const __bf16* src, int tid) {
#pragma unroll
  for (int it = 0; it < 8; ++it) {
    int i = tid + it * 256;
    int rr = i >> 7;
    int c8 = i & 127;
    bf16x8 v = *(const bf16x8*)(src + (size_t)rr * 1024 + c8 * 8);
    *(bf16x8*)(dst + rr * 2048 + ((c8 * 16) ^ ((rr & 7) << 4))) = v;
  }
}

// ---- half-K GEMM burst (row-major A), transposed MFMA: D' = W x state^T ----
template<int NS>
__device__ inline void gemm_half(const char* sm, const __bf16* __restrict__ A,
                                 int rowbase, int lane, int kb0, f32x4v (&acc)[NS]) {
  const int r = lane & 15, q = lane >> 4;
  const __bf16* Ap = A + (size_t)(rowbase + r) * 1024 + q * 8;
  bf16x8 a[16];
#pragma unroll
  for (int i = 0; i < 16; ++i) a[i] = *(const bf16x8*)(Ap + (kb0 + i) * 32);
  __builtin_amdgcn_sched_barrier(0);   // pin: all 16 loads issued before MFMAs
  __builtin_amdgcn_s_setprio(1);
#pragma unroll
  for (int i = 0; i < 16; ++i) {
    const int kb = kb0 + i;
    const int byteo = (kb * 64 + q * 16) ^ ((r & 7) << 4);
#pragma unroll
    for (int s = 0; s < NS; ++s) {
      bf16x8 b = *(const bf16x8*)(sm + s * 32768 + r * 2048 + byteo);
      acc[s] = MFMA16(b, a[i], acc[s]);   // weights as A-operand (transposed D)
    }
  }
  __builtin_amdgcn_s_setprio(0);
}

// ---- half-K GEMM burst, STRIP-BLOCKED A ([64 strips][128 rows][16 cols]) ----
// k = kb*32 + q*8 + j  ->  strip 2*kb + (q>>1), cc = (q&1)*8 + j. Same nominal
// k on both operands -> contraction correct independent of HW k-slot map.
template<int NS>
__device__ inline void gemm_half_sb(const char* sm, const __bf16* __restrict__ A,
                                    int rowbase, int lane, int kb0, f32x4v (&acc)[NS]) {
  const int r = lane & 15, q = lane >> 4;
  const __bf16* Ap = A + ((size_t)(q >> 1) * 128 + (rowbase + r)) * 16 + (q & 1) * 8;
  bf16x8 a[16];
#pragma unroll
  for (int i = 0; i < 16; ++i) a[i] = *(const bf16x8*)(Ap + (size_t)(kb0 + i) * 4096);
  __builtin_amdgcn_sched_barrier(0);
  __builtin_amdgcn_s_setprio(1);
#pragma unroll
  for (int i = 0; i < 16; ++i) {
    const int kb = kb0 + i;
    const int byteo = (kb * 64 + q * 16) ^ ((r & 7) << 4);
#pragma unroll
    for (int s = 0; s < NS; ++s) {
      bf16x8 b = *(const bf16x8*)(sm + s * 32768 + r * 2048 + byteo);
      acc[s] = MFMA16(b, a[i], acc[s]);
    }
  }
  __builtin_amdgcn_s_setprio(0);
}

// ---- full-K GEMM burst (32 chunks, row-major A), transposed ----
template<int NS>
__device__ inline void gemm_burst(const char* sm, const __bf16* __restrict__ A,
                                  int rowbase, int lane, f32x4v (&acc)[NS]) {
  const int r = lane & 15, q = lane >> 4;
  const __bf16* Ap = A + (size_t)(rowbase + r) * 1024 + q * 8;
  bf16x8 a[32];
#pragma unroll
  for (int kb = 0; kb < 32; ++kb) a[kb] = *(const bf16x8*)(Ap + kb * 32);
  __builtin_amdgcn_sched_barrier(0);
  __builtin_amdgcn_s_setprio(1);
#pragma unroll
  for (int kb = 0; kb < 32; ++kb) {
    const int byteo = (kb * 64 + q * 16) ^ ((r & 7) << 4);
#pragma unroll
    for (int s = 0; s < NS; ++s) {
      bf16x8 b = *(const bf16x8*)(sm + s * 32768 + r * 2048 + byteo);
      acc[s] = MFMA16(b, a[kb], acc[s]);
    }
  }
  __builtin_amdgcn_s_setprio(0);
}

// ---- full-K GEMM burst (32 chunks), STRIP-BLOCKED A ----
template<int NS>
__device__ inline void gemm_burst_sb(const char* sm, const __bf16* __restrict__ A,
                                     int rowbase, int lane, f32x4v (&acc)[NS]) {
  const int r = lane & 15, q = lane >> 4;
  const __bf16* Ap = A + ((size_t)(q >> 1) * 128 + (rowbase + r)) * 16 + (q & 1) * 8;
  bf16x8 a[32];
#pragma unroll
  for (int kb = 0; kb < 32; ++kb) a[kb] = *(const bf16x8*)(Ap + (size_t)kb * 4096);
  __builtin_amdgcn_sched_barrier(0);
  __builtin_amdgcn_s_setprio(1);
#pragma unroll
  for (int kb = 0; kb < 32; ++kb) {
    const int byteo = (kb * 64 + q * 16) ^ ((r & 7) << 4);
#pragma unroll
    for (int s = 0; s < NS; ++s) {
      bf16x8 b = *(const bf16x8*)(sm + s * 32768 + r * 2048 + byteo);
      acc[s] = MFMA16(b, a[kb], acc[s]);
    }
  }
  __builtin_amdgcn_s_setprio(0);
}

// ------------------------- persistent recurrent kernel -------------------------
// XCD-affine roles: xcd = wg&7, role = xcd>>1. Two batch halves pipeline through
// the roles phase-shifted (r0-proven). Transposed-MFMA epilogue: lane holds
// row = rowbase + (lane&15), cols = c0 + (lane>>4)*4 + 0..3.
// r8 delta vs r6 (passing): h2b ALSO strip-blocked [64][128][16] (h1b validated
// in r6). h0b stays ROW-MAJOR (isolating r7's failure). Sync byte-identical.
__global__ void __launch_bounds__(NT, 2) gru_persist(
    const float* __restrict__ Whh0, const float* __restrict__ Wih1,
    const float* __restrict__ Whh1, const float* __restrict__ Wlin,
    const __bf16* __restrict__ gi0b, const float* __restrict__ G,
    __bf16* __restrict__ h0b, __bf16* __restrict__ h1b,
    __bf16* __restrict__ h2b, __bf16* __restrict__ gh1b,
    float* __restrict__ out, int* flags)
{
  __shared__ char sm[107008];
  float* h2s = (float*)(sm + 98304);          // [128][17] f32 (pad 17), role 2
  const int tid = threadIdx.x, wg = blockIdx.x;
  const int wv = tid >> 6, lane = tid & 63;
  const int xcd = wg & 7;
  const int role = xcd >> 1;
  const int g = ((wg >> 3) << 1) | (xcd & 1); // 0..63
  const int c0 = g * 16;
  const int chg = (g >= 32);                  // my column half
  const int r = lane & 15, q = lane >> 4;
  const bool gw = (wv < 4);                   // GEMM waves (4 x 16 rows = 64-row half)

  if (role == 0) {
    stage_strip(sm,         Whh0 + (size_t)c0 * 1024,          1024, tid);
    stage_strip(sm + 32768, Whh0 + (size_t)(1024 + c0) * 1024, 1024, tid);
    stage_strip(sm + 65536, Whh0 + (size_t)(2048 + c0) * 1024, 1024, tid);
  } else if (role == 1) {
    stage_strip(sm,         Whh1 + (size_t)c0 * 1024,          1024, tid);
    stage_strip(sm + 32768, Whh1 + (size_t)(1024 + c0) * 1024, 1024, tid);
    stage_strip(sm + 65536, Whh1 + (size_t)(2048 + c0) * 1024, 1024, tid);
  } else if (role == 2) {
    stage_strip(sm,         Wih1 + (size_t)c0 * 1024,          1024, tid);
    stage_strip(sm + 32768, Wih1 + (size_t)(1024 + c0) * 1024, 1024, tid);
    stage_strip(sm + 65536, Wih1 + (size_t)(2048 + c0) * 1024, 1024, tid);
    for (int i = tid; i < 2048; i += NT) {    // h2 f32 master <- G[1] slice (all rows)
      int row = i >> 4, cc = i & 15;
      h2s[row * 17 + cc] = G[131072 + row * 1024 + c0 + cc];
    }
  } else {
    stage_strip(sm,         Wlin + (size_t)c0 * 2048,        2048, tid); // linL
    stage_strip(sm + 32768, Wlin + (size_t)c0 * 2048 + 1024, 2048, tid); // linR
  }
  __syncthreads();

  if (role == 0) {
    for (int t = 0; t < TT; ++t) {
      __bf16* h1bP = h1b + (size_t)(t & 1) * 131072;   // parity buffer
#pragma unroll
      for (int h = 0; h < 2; ++h) {
        const int rowbase = h * 64 + wv * 16;
        const int row = rowbase + r;
        // gi0 vectors: flag-independent — issue before waits to hide LLC latency
        bf16x4 vgr, vgz, vgn;
        if (gw) {
          const __bf16* gp = gi0b + ((size_t)t * 128 + row) * 3072 + c0 + q * 4;
          vgr = *(const bf16x4*)(gp);
          vgz = *(const bf16x4*)(gp + 1024);
          vgn = *(const bf16x4*)(gp + 2048);
        }
        f32x4v acc[3];
#pragma unroll
        for (int s = 0; s < 3; ++s) { f32x4v z = {0,0,0,0}; acc[s] = z; }
        cwait1(CPTR(3,h,0), 32 * t, tid);          // h0 cols 0..511 ready
        if (gw) gemm_half<3>(sm, h0b, rowbase, lane, 0, acc);
        cwait1(CPTR(3,h,1), 32 * t, tid);          // h0 cols 512..1023 ready
        if (gw) {
          bf16x4 vph = *(const bf16x4*)(h0b + (size_t)row * 1024 + c0 + q * 4);
          gemm_half<3>(sm, h0b, rowbase, lane, 16, acc);
          f32x4v o;
#pragma unroll
          for (int gg = 0; gg < 4; ++gg) {
            float rv = fsig((float)vgr[gg] + acc[0][gg]);
            float zv = fsig((float)vgz[gg] + acc[1][gg]);
            float nv = ftanh((float)vgn[gg] + rv * acc[2][gg]);
            o[gg] = (1.f - zv) * nv + zv * (float)vph[gg];
          }
          // strip-blocked h1: dense 2KB block per WG per phase
          ucst64(h1bP + ((size_t)g * 128 + row) * 16 + q * 4, o);
        }
        SIGC(0, h);
      }
    }
  } else if (role == 1) {
    for (int t = 0; t < TT; ++t) {
#pragma unroll
      for (int h = 0; h < 2; ++h) {
        cwait2(CPTR(2,h,0), CPTR(2,h,1), 32 * t, tid, lane);  // h2(t-1) ready
        if (gw) {
          const int rowbase = h * 64 + wv * 16;
          const int row = rowbase + r;
          f32x4v acc[3];
#pragma unroll
          for (int s = 0; s < 3; ++s) { f32x4v z = {0,0,0,0}; acc[s] = z; }
          gemm_burst_sb<3>(sm, h2b, rowbase, lane, acc);
          size_t base = (size_t)row * 3072 + c0 + q * 4;
          ucst64(gh1b + base,        acc[0]);
          ucst64(gh1b + base + 1024, acc[1]);
          ucst64(gh1b + base + 2048, acc[2]);
        }
        SIGC(1, h);
      }
    }
  } else if (role == 2) {
    for (int t = 0; t < TT; ++t) {
      const __bf16* h1bP = h1b + (size_t)(t & 1) * 131072;
#pragma unroll
      for (int h = 0; h < 2; ++h) {
        const int rowbase = h * 64 + wv * 16;
        const int row = rowbase + r;
        // stage A: gh1 ready (parallel with role0) -> prefetch vectors early.
        cwait2(CPTR(1,h,0), CPTR(1,h,1), 32 * (t + 1), tid, lane);
        bf16x4 vh0, vh1, vh2;
        if (gw) {
          const __bf16* hp = gh1b + (size_t)row * 3072 + c0 + q * 4;
          vh0 = *(const bf16x4*)(hp);
          vh1 = *(const bf16x4*)(hp + 1024);
          vh2 = *(const bf16x4*)(hp + 2048);
        }
        // stage B: h1 (strip-blocked) in column halves
        f32x4v acc[3];
#pragma unroll
        for (int s = 0; s < 3; ++s) { f32x4v z = {0,0,0,0}; acc[s] = z; }
        cwait1(CPTR(0,h,0), 32 * (t + 1), tid);
        if (gw) gemm_half_sb<3>(sm, h1bP, rowbase, lane, 0, acc);
        cwait1(CPTR(0,h,1), 32 * (t + 1), tid);
        if (gw) {
          gemm_half_sb<3>(sm, h1bP, rowbase, lane, 16, acc);
          f32x4v o;
#pragma unroll
          for (int gg = 0; gg < 4; ++gg) {
            float rv = fsig(acc[0][gg] + (float)vh0[gg]);
            float zv = fsig(acc[1][gg] + (float)vh1[gg]);
            float nv = ftanh(acc[2][gg] + rv * (float)vh2[gg]);
            float hp2 = h2s[row * 17 + q * 4 + gg];
            float h2 = (1.f - zv) * nv + zv * hp2;
            h2s[row * 17 + q * 4 + gg] = h2;
            o[gg] = h2;
          }
          // strip-blocked h2: dense 2KB block per WG per phase
          ucst64(h2b + ((size_t)g * 128 + row) * 16 + q * 4, o);
        }
        SIGC(2, h);
      }
    }
  } else {
    for (int t = 0; t < TT; ++t) {
#pragma unroll
      for (int h = 0; h < 2; ++h) {
        const int rowbase = h * 64 + wv * 16;
        const int row = rowbase + r;
        cwait2(CPTR(3,h,0), CPTR(3,h,1), 32 * t, tid, lane);  // h0(t-1) fully written
        f32x4v accL[1];
        { f32x4v z = {0,0,0,0}; accL[0] = z; }
        if (gw) gemm_burst<1>(sm, h0b, rowbase, lane, accL);
        // linR in column halves as h2 arrives (strip-blocked h2)
        f32x4v accR[1];
        { f32x4v z = {0,0,0,0}; accR[0] = z; }
        cwait1(CPTR(2,h,0), 32 * (t + 1), tid);
        if (gw) gemm_half_sb<1>(sm + 32768, h2b, rowbase, lane, 0, accR);
        cwait1(CPTR(2,h,1), 32 * (t + 1), tid);
        if (gw) {
          gemm_half_sb<1>(sm + 32768, h2b, rowbase, lane, 16, accR);
          f32x4v o;
#pragma unroll
          for (int gg = 0; gg < 4; ++gg)
            o[gg] = ftanh(accL[0][gg] + accR[0][gg]);
          ucst64(h0b + (size_t)row * 1024 + c0 + q * 4, o);
          *(f32x4v*)(out + ((size_t)row * 128 + t) * 1024 + c0 + q * 4) = o;
        }
        SIGC(3, h);
      }
    }
  }
}

// ------------------------- gi0 precompute -> gi0b[t][b][3H] bf16 -------------------------
// Grid: 48 n-tiles x 32 mi-groups. (r4 layout, unchanged.)
__global__ void __launch_bounds__(256) gi0_kernel(const float* __restrict__ X,
                                                  const __bf16* __restrict__ Wih0b,
                                                  __bf16* __restrict__ gi0b) {
  __shared__ char sm[131072];
  const int tid = threadIdx.x, wv = tid >> 6, lane = tid & 63;
  const int bi = blockIdx.x;
  const int n = bi % 48, mg = bi / 48;
#pragma unroll
  for (int s = 0; s < 4; ++s)
    stage_strip_b16(sm + s * 32768, Wih0b + (size_t)(n * 64 + s * 16) * 1024, tid);
  __syncthreads();
  const int r = lane & 15, q = lane >> 4;
  for (int mi = mg * 4; mi < mg * 4 + 4; ++mi) {
    f32x4v acc[4][2];
#pragma unroll
    for (int s = 0; s < 4; ++s) { f32x4v z = {0,0,0,0}; acc[s][0] = z; acc[s][1] = z; }
    const float* Ap = X + ((size_t)mi * 128 + wv * 32 + r) * 1024 + q * 8;
#pragma unroll 4
    for (int kb = 0; kb < 32; ++kb) {
      f32x4v x0a = *(const f32x4v*)(Ap + kb * 32);
      f32x4v x0b = *(const f32x4v*)(Ap + kb * 32 + 4);
      f32x4v x1a = *(const f32x4v*)(Ap + 16384 + kb * 32);
      f32x4v x1b = *(const f32x4v*)(Ap + 16384 + kb * 32 + 4);
      bf16x8 a0, a1;
#pragma unroll
      for (int j = 0; j < 4; ++j) {
        a0[j] = (__bf16)x0a[j]; a0[4 + j] = (__bf16)x0b[j];
        a1[j] = (__bf16)x1a[j]; a1[4 + j] = (__bf16)x1b[j];
      }
      const int byteo = (kb * 64 + q * 16) ^ ((r & 7) << 4);
#pragma unroll
      for (int s = 0; s < 4; ++s) {
        bf16x8 b = *(const bf16x8*)(sm + s * 32768 + r * 2048 + byteo);
        acc[s][0] = MFMA16(a0, b, acc[s][0]);
        acc[s][1] = MFMA16(a1, b, acc[s][1]);
      }
    }
#pragma unroll
    for (int s = 0; s < 4; ++s)
#pragma unroll
      for (int mf = 0; mf < 2; ++mf)
#pragma unroll
        for (int gg = 0; gg < 4; ++gg) {
          int trow = wv * 32 + mf * 16 + q * 4 + gg;     // = t
          gi0b[((size_t)trow * 128 + mi) * 3072 + n * 64 + s * 16 + r] = (__bf16)acc[s][mf][gg];
        }
  }
}

// ------------------------- prep: Wih0->bf16, state init (h2b strip-blocked), flags ----
__global__ void __launch_bounds__(256) prep3(const float* __restrict__ Wih0f,
                                             const float* __restrict__ G,
                                             __bf16* Wih0b,
                                             __bf16* h0b, __bf16* h2b, int* flags) {
  long c = (long)blockIdx.x * 256 + threadIdx.x;
  if (c < 786432) {
    f32x4v v = *(const f32x4v*)(Wih0f + c * 4);
    bf16x4 o;
#pragma unroll
    for (int j = 0; j < 4; ++j) o[j] = (__bf16)v[j];
    *(bf16x4*)(Wih0b + c * 4) = o;
  } else if (c < 786432 + 131072) {
    long i = c - 786432;                       // h0b row-major (r6)
    h0b[i] = (__bf16)G[i];
  } else if (c < 786432 + 262144) {
    long i = c - 786432 - 131072;              // h2b strip-blocked [g][row][cc]
    int gg = i >> 11, row = (i >> 4) & 127, cc = i & 15;
    h2b[i] = (__bf16)G[131072 + row * 1024 + gg * 16 + cc];
  } else if (c < 786432 + 262144 + 8192) {
    flags[c - 786432 - 262144] = 0;
  }
}

// ------------------------- final LayerNorm (ddof=1, denom std+eps) -------------------------
__global__ void __launch_bounds__(256) ln_kernel(float* __restrict__ out,
                                                 const float* __restrict__ a2,
                                                 const float* __restrict__ b2) {
  int wv = threadIdx.x >> 6, lane = threadIdx.x & 63;
  size_t row = (size_t)blockIdx.x * 4 + wv;
  float* p = out + row * 1024;
  f32x4v v[4];
  float s = 0.f, ss = 0.f;
#pragma unroll
  for (int i = 0; i < 4; ++i) {
    v[i] = *(const f32x4v*)(p + (i * 64 + lane) * 4);
#pragma unroll
    for (int j = 0; j < 4; ++j) { s += v[i][j]; ss += v[i][j] * v[i][j]; }
  }
#pragma unroll
  for (int o = 32; o > 0; o >>= 1) { s += __shfl_xor(s, o); ss += __shfl_xor(ss, o); }
  float mean = s * (1.f / 1024.f);
  float var = (ss - 1024.f * mean * mean) * (1.f / 1023.f);
  var = fmaxf(var, 0.f);
  float inv = 1.f / (sqrtf(var) + 1e-6f);
#pragma unroll
  for (int i = 0; i < 4; ++i) {
    int c0 = (i * 64 + lane) * 4;
    f32x4v gA = *(const f32x4v*)(a2 + c0);
    f32x4v bo = *(const f32x4v*)(b2 + c0);
    f32x4v o;
#pragma unroll
    for (int j = 0; j < 4; ++j) o[j] = gA[j] * (v[i][j] - mean) * inv + bo[j];
    *(f32x4v*)(p + c0) = o;
  }
}

extern "C" void kernel_launch(void* const* d_in, const int* in_sizes, int n_in,
                              void* d_out, int out_size, void* d_ws, size_t ws_size,
                              hipStream_t stream) {
  const float* X    = (const float*)d_in[0];
  const float* G    = (const float*)d_in[1];
  // d_in[2] = L : dead (attention result discarded in reference)
  const float* Wih0 = (const float*)d_in[3];
  const float* Whh0 = (const float*)d_in[4];
  const float* Wih1 = (const float*)d_in[5];
  const float* Whh1 = (const float*)d_in[6];
  const float* Wlin = (const float*)d_in[7];
  const float* a2   = (const float*)d_in[8];
  const float* b2   = (const float*)d_in[9];
  float* out = (float*)d_out;

  char* ws = (char*)d_ws;
  size_t off = 0;
  auto take = [&](size_t n) { char* p = ws + off; off += (n + 255) & ~(size_t)255; return p; };
  __bf16* Wih0b = (__bf16*)take((size_t)3072 * 1024 * 2);
  __bf16* gi0b  = (__bf16*)take((size_t)16384 * 3072 * 2);   // 96 MB, [t][b][3H]
  __bf16* gh1b  = (__bf16*)take((size_t)128 * 3072 * 2);
  __bf16* h0b   = (__bf16*)take((size_t)BB * HH * 2);        // row-major (r6)
  __bf16* h1b   = (__bf16*)take((size_t)BB * HH * 2 * 2);    // parity dbuf, strip-blocked
  __bf16* h2b   = (__bf16*)take((size_t)BB * HH * 2);        // strip-blocked (new)
  int*    flags = (int*)take(8192 * 4);                      // 16 counters, 64B/line
  if (off > ws_size) return; // workspace too small: fail loudly (output stays poisoned)

  prep3<<<4128, 256, 0, stream>>>(Wih0, G, Wih0b, h0b, h2b, flags);
  gi0_kernel<<<1536, 256, 0, stream>>>(X, Wih0b, gi0b);
  gru_persist<<<NWG, NT, 0, stream>>>(Whh0, Wih1, Whh1, Wlin, gi0b, G,
                                      h0b, h1b, h2b, gh1b, out, flags);
  ln_kernel<<<4096, 256, 0, stream>>>(out, a2, b2);
}

// Round 9
// 3930.202 us; speedup vs baseline: 1.1361x; 1.1361x over previous
//
#include <hip/hip_runtime.h>
#include <hip/hip_bf16.h>

#define BB 128
#define TT 128
#define HH 1024
#define NWG 256
#define NT 512

typedef __bf16 bf16x8 __attribute__((ext_vector_type(8)));
typedef __bf16 bf16x4 __attribute__((ext_vector_type(4)));
typedef float  f32x4v __attribute__((ext_vector_type(4)));

#define MFMA16(a,b,c) __builtin_amdgcn_mfma_f32_16x16x32_bf16(a,b,c,0,0,0)

__device__ inline float fsig(float x) {
  x = fminf(fmaxf(x, -30.f), 30.f);
  return 1.f / (1.f + __expf(-x));
}
__device__ inline float ftanh(float x) {
  x = fminf(fmaxf(x, -15.f), 15.f);
  float e = __expf(2.f * x);
  return (e - 1.f) / (e + 1.f);
}
// UC (LLC coherent-point) 8B store for cross-WG state: 4 consecutive bf16
__device__ inline void ucst64(__bf16* p, const f32x4v v) {
  union { unsigned long long u; __bf16 b[4]; } c;
#pragma unroll
  for (int j = 0; j < 4; ++j) c.b[j] = (__bf16)v[j];
  __hip_atomic_store((unsigned long long*)p, c.u, __ATOMIC_RELAXED, __HIP_MEMORY_SCOPE_AGENT);
}

// ---- DAG sync: aggregate monotone counters (r4 mechanism, unchanged). One
// counter per (role, batch-half, column-half), each on its own 64B line.
#define CPTR(role,bh,ch) (flags + (((role)*2+(bh))*2+(ch))*16)

#define SIGC(role,bh) do { \
  __syncthreads(); \
  if (tid == 0) \
    __hip_atomic_fetch_add(CPTR(role,bh,chg), 1, __ATOMIC_RELAXED, __HIP_MEMORY_SCOPE_AGENT); \
} while (0)

__device__ inline void cwait1(const int* C, int tgt, int tid) {
  if (tid < 64) {
    while (__hip_atomic_load(C, __ATOMIC_RELAXED, __HIP_MEMORY_SCOPE_AGENT) < tgt)
      __builtin_amdgcn_s_sleep(1);
    __builtin_amdgcn_fence(__ATOMIC_ACQUIRE, "agent");
  }
  __syncthreads();
  __builtin_amdgcn_sched_barrier(0);
}
__device__ inline void cwait2(const int* C0, const int* C1, int tgt, int tid, int lane) {
  if (tid < 64) {
    const int* P = (lane < 32) ? C0 : C1;
    while (__hip_atomic_load(P, __ATOMIC_RELAXED, __HIP_MEMORY_SCOPE_AGENT) < tgt)
      __builtin_amdgcn_s_sleep(1);
    __builtin_amdgcn_fence(__ATOMIC_ACQUIRE, "agent");
  }
  __syncthreads();
  __builtin_amdgcn_sched_barrier(0);
}

// ---- stage one 16x1024 f32 weight strip into LDS as swizzled bf16 (32KB), NT=512 ----
__device__ inline void stage_strip(char* dst, const float* src, int rstride, int tid) {
#pragma unroll
  for (int it = 0; it < 8; ++it) {
    int i = tid + it * NT;
    int rr = i >> 8;
    int c4 = i & 255;
    f32x4v v = *(const f32x4v*)(src + (size_t)rr * rstride + c4 * 4);
    bf16x4 o;
#pragma unroll
    for (int j = 0; j < 4; ++j) o[j] = (__bf16)v[j];
    *(bf16x4*)(dst + rr * 2048 + ((c4 * 8) ^ ((rr & 7) << 4))) = o;
  }
}

// ---- stage one 16x1024 bf16 strip into LDS swizzled (32KB), 256 threads ----
__device__ inline void stage_strip_b16(char* dst, const __bf16* src, int tid) {
#pragma unroll
  for (int it = 0; it < 8; ++it) {
    int i = tid + it * 256;
    int rr = i >> 7;
    int c8 = i & 127;
    bf16x8 v = *(const bf16x8*)(src + (size_t)rr * 1024 + c8 * 8);
    *(bf16x8*)(dst + rr * 2048 + ((c8 * 16) ^ ((rr & 7) << 4))) = v;
  }
}

// ---- half-K GEMM burst (row-major A), transposed MFMA: D' = W x state^T ----
template<int NS>
__device__ inline void gemm_half(const char* sm, const __bf16* __restrict__ A,
                                 int rowbase, int lane, int kb0, f32x4v (&acc)[NS]) {
  const int r = lane & 15, q = lane >> 4;
  const __bf16* Ap = A + (size_t)(rowbase + r) * 1024 + q * 8;
  bf16x8 a[16];
#pragma unroll
  for (int i = 0; i < 16; ++i) a[i] = *(const bf16x8*)(Ap + (kb0 + i) * 32);
  __builtin_amdgcn_sched_barrier(0);   // pin: all 16 loads issued before MFMAs
  __builtin_amdgcn_s_setprio(1);
#pragma unroll
  for (int i = 0; i < 16; ++i) {
    const int kb = kb0 + i;
    const int byteo = (kb * 64 + q * 16) ^ ((r & 7) << 4);
#pragma unroll
    for (int s = 0; s < NS; ++s) {
      bf16x8 b = *(const bf16x8*)(sm + s * 32768 + r * 2048 + byteo);
      acc[s] = MFMA16(b, a[i], acc[s]);   // weights as A-operand (transposed D)
    }
  }
  __builtin_amdgcn_s_setprio(0);
}

// ---- half-K GEMM burst, STRIP-BLOCKED A ([64 strips][128 rows][16 cols]) ----
// k = kb*32 + q*8 + j  ->  strip 2*kb + (q>>1), cc = (q&1)*8 + j. Same nominal
// k on both operands -> contraction correct independent of HW k-slot map.
template<int NS>
__device__ inline void gemm_half_sb(const char* sm, const __bf16* __restrict__ A,
                                    int rowbase, int lane, int kb0, f32x4v (&acc)[NS]) {
  const int r = lane & 15, q = lane >> 4;
  const __bf16* Ap = A + ((size_t)(q >> 1) * 128 + (rowbase + r)) * 16 + (q & 1) * 8;
  bf16x8 a[16];
#pragma unroll
  for (int i = 0; i < 16; ++i) a[i] = *(const bf16x8*)(Ap + (size_t)(kb0 + i) * 4096);
  __builtin_amdgcn_sched_barrier(0);
  __builtin_amdgcn_s_setprio(1);
#pragma unroll
  for (int i = 0; i < 16; ++i) {
    const int kb = kb0 + i;
    const int byteo = (kb * 64 + q * 16) ^ ((r & 7) << 4);
#pragma unroll
    for (int s = 0; s < NS; ++s) {
      bf16x8 b = *(const bf16x8*)(sm + s * 32768 + r * 2048 + byteo);
      acc[s] = MFMA16(b, a[i], acc[s]);
    }
  }
  __builtin_amdgcn_s_setprio(0);
}

// ---- full-K GEMM burst (32 chunks, row-major A), transposed ----
template<int NS>
__device__ inline void gemm_burst(const char* sm, const __bf16* __restrict__ A,
                                  int rowbase, int lane, f32x4v (&acc)[NS]) {
  const int r = lane & 15, q = lane >> 4;
  const __bf16* Ap = A + (size_t)(rowbase + r) * 1024 + q * 8;
  bf16x8 a[32];
#pragma unroll
  for (int kb = 0; kb < 32; ++kb) a[kb] = *(const bf16x8*)(Ap + kb * 32);
  __builtin_amdgcn_sched_barrier(0);
  __builtin_amdgcn_s_setprio(1);
#pragma unroll
  for (int kb = 0; kb < 32; ++kb) {
    const int byteo = (kb * 64 + q * 16) ^ ((r & 7) << 4);
#pragma unroll
    for (int s = 0; s < NS; ++s) {
      bf16x8 b = *(const bf16x8*)(sm + s * 32768 + r * 2048 + byteo);
      acc[s] = MFMA16(b, a[kb], acc[s]);
    }
  }
  __builtin_amdgcn_s_setprio(0);
}

// ------------------------- persistent recurrent kernel -------------------------
// XCD-affine roles: xcd = wg&7, role = xcd>>1. Two batch halves pipeline through
// the roles phase-shifted (r0-proven). Transposed-MFMA epilogue: lane holds
// row = rowbase + (lane&15), cols = c0 + (lane>>4)*4 + 0..3.
// r9 deltas vs r6 (passing, 3393us): (1) gh1b strip-blocked [g][3][128][16] —
// pure point-to-point arc (role1-WG-g -> role2-WG-g), so the r8 multi-consumer
// channel-hotspot regression can't apply; (2) role3's out store moved after
// SIGC (off the h0 critical path). h0b/h2b stay ROW-MAJOR (r7/r8 lessons).
__global__ void __launch_bounds__(NT, 2) gru_persist(
    const float* __restrict__ Whh0, const float* __restrict__ Wih1,
    const float* __restrict__ Whh1, const float* __restrict__ Wlin,
    const __bf16* __restrict__ gi0b, const float* __restrict__ G,
    __bf16* __restrict__ h0b, __bf16* __restrict__ h1b,
    __bf16* __restrict__ h2b, __bf16* __restrict__ gh1b,
    float* __restrict__ out, int* flags)
{
  __shared__ char sm[107008];
  float* h2s = (float*)(sm + 98304);          // [128][17] f32 (pad 17), role 2
  const int tid = threadIdx.x, wg = blockIdx.x;
  const int wv = tid >> 6, lane = tid & 63;
  const int xcd = wg & 7;
  const int role = xcd >> 1;
  const int g = ((wg >> 3) << 1) | (xcd & 1); // 0..63
  const int c0 = g * 16;
  const int chg = (g >= 32);                  // my column half
  const int r = lane & 15, q = lane >> 4;
  const bool gw = (wv < 4);                   // GEMM waves (4 x 16 rows = 64-row half)

  if (role == 0) {
    stage_strip(sm,         Whh0 + (size_t)c0 * 1024,          1024, tid);
    stage_strip(sm + 32768, Whh0 + (size_t)(1024 + c0) * 1024, 1024, tid);
    stage_strip(sm + 65536, Whh0 + (size_t)(2048 + c0) * 1024, 1024, tid);
  } else if (role == 1) {
    stage_strip(sm,         Whh1 + (size_t)c0 * 1024,          1024, tid);
    stage_strip(sm + 32768, Whh1 + (size_t)(1024 + c0) * 1024, 1024, tid);
    stage_strip(sm + 65536, Whh1 + (size_t)(2048 + c0) * 1024, 1024, tid);
  } else if (role == 2) {
    stage_strip(sm,         Wih1 + (size_t)c0 * 1024,          1024, tid);
    stage_strip(sm + 32768, Wih1 + (size_t)(1024 + c0) * 1024, 1024, tid);
    stage_strip(sm + 65536, Wih1 + (size_t)(2048 + c0) * 1024, 1024, tid);
    for (int i = tid; i < 2048; i += NT) {    // h2 f32 master <- G[1] slice (all rows)
      int row = i >> 4, cc = i & 15;
      h2s[row * 17 + cc] = G[131072 + row * 1024 + c0 + cc];
    }
  } else {
    stage_strip(sm,         Wlin + (size_t)c0 * 2048,        2048, tid); // linL
    stage_strip(sm + 32768, Wlin + (size_t)c0 * 2048 + 1024, 2048, tid); // linR
  }
  __syncthreads();

  if (role == 0) {
    for (int t = 0; t < TT; ++t) {
      __bf16* h1bP = h1b + (size_t)(t & 1) * 131072;   // parity buffer
#pragma unroll
      for (int h = 0; h < 2; ++h) {
        const int rowbase = h * 64 + wv * 16;
        const int row = rowbase + r;
        // gi0 vectors: flag-independent — issue before waits to hide LLC latency
        bf16x4 vgr, vgz, vgn;
        if (gw) {
          const __bf16* gp = gi0b + ((size_t)t * 128 + row) * 3072 + c0 + q * 4;
          vgr = *(const bf16x4*)(gp);
          vgz = *(const bf16x4*)(gp + 1024);
          vgn = *(const bf16x4*)(gp + 2048);
        }
        f32x4v acc[3];
#pragma unroll
        for (int s = 0; s < 3; ++s) { f32x4v z = {0,0,0,0}; acc[s] = z; }
        cwait1(CPTR(3,h,0), 32 * t, tid);          // h0 cols 0..511 ready
        if (gw) gemm_half<3>(sm, h0b, rowbase, lane, 0, acc);
        cwait1(CPTR(3,h,1), 32 * t, tid);          // h0 cols 512..1023 ready
        if (gw) {
          bf16x4 vph = *(const bf16x4*)(h0b + (size_t)row * 1024 + c0 + q * 4);
          gemm_half<3>(sm, h0b, rowbase, lane, 16, acc);
          f32x4v o;
#pragma unroll
          for (int gg = 0; gg < 4; ++gg) {
            float rv = fsig((float)vgr[gg] + acc[0][gg]);
            float zv = fsig((float)vgz[gg] + acc[1][gg]);
            float nv = ftanh((float)vgn[gg] + rv * acc[2][gg]);
            o[gg] = (1.f - zv) * nv + zv * (float)vph[gg];
          }
          // strip-blocked h1: dense 2KB block per WG per phase
          ucst64(h1bP + ((size_t)g * 128 + row) * 16 + q * 4, o);
        }
        SIGC(0, h);
      }
    }
  } else if (role == 1) {
    for (int t = 0; t < TT; ++t) {
#pragma unroll
      for (int h = 0; h < 2; ++h) {
        cwait2(CPTR(2,h,0), CPTR(2,h,1), 32 * t, tid, lane);  // h2(t-1) ready
        if (gw) {
          const int rowbase = h * 64 + wv * 16;
          const int row = rowbase + r;
          f32x4v acc[3];
#pragma unroll
          for (int s = 0; s < 3; ++s) { f32x4v z = {0,0,0,0}; acc[s] = z; }
          gemm_burst<3>(sm, h2b, rowbase, lane, acc);
          // strip-blocked gh1 [g][3][128][16]: dense 6KB point-to-point block
          size_t base = (((size_t)g * 3) * 128 + row) * 16 + q * 4;
          ucst64(gh1b + base,        acc[0]);
          ucst64(gh1b + base + 2048, acc[1]);
          ucst64(gh1b + base + 4096, acc[2]);
        }
        SIGC(1, h);
      }
    }
  } else if (role == 2) {
    for (int t = 0; t < TT; ++t) {
      const __bf16* h1bP = h1b + (size_t)(t & 1) * 131072;
#pragma unroll
      for (int h = 0; h < 2; ++h) {
        const int rowbase = h * 64 + wv * 16;
        const int row = rowbase + r;
        // stage A: gh1 ready (parallel with role0) -> prefetch vectors early.
        cwait2(CPTR(1,h,0), CPTR(1,h,1), 32 * (t + 1), tid, lane);
        bf16x4 vh0, vh1, vh2;
        if (gw) {
          const __bf16* hp = gh1b + (((size_t)g * 3) * 128 + row) * 16 + q * 4;
          vh0 = *(const bf16x4*)(hp);
          vh1 = *(const bf16x4*)(hp + 2048);
          vh2 = *(const bf16x4*)(hp + 4096);
        }
        // stage B: h1 (strip-blocked) in column halves
        f32x4v acc[3];
#pragma unroll
        for (int s = 0; s < 3; ++s) { f32x4v z = {0,0,0,0}; acc[s] = z; }
        cwait1(CPTR(0,h,0), 32 * (t + 1), tid);
        if (gw) gemm_half_sb<3>(sm, h1bP, rowbase, lane, 0, acc);
        cwait1(CPTR(0,h,1), 32 * (t + 1), tid);
        if (gw) {
          gemm_half_sb<3>(sm, h1bP, rowbase, lane, 16, acc);
          f32x4v o;
#pragma unroll
          for (int gg = 0; gg < 4; ++gg) {
            float rv = fsig(acc[0][gg] + (float)vh0[gg]);
            float zv = fsig(acc[1][gg] + (float)vh1[gg]);
            float nv = ftanh(acc[2][gg] + rv * (float)vh2[gg]);
            float hp2 = h2s[row * 17 + q * 4 + gg];
            float h2 = (1.f - zv) * nv + zv * hp2;
            h2s[row * 17 + q * 4 + gg] = h2;
            o[gg] = h2;
          }
          ucst64(h2b + (size_t)row * 1024 + c0 + q * 4, o);
        }
        SIGC(2, h);
      }
    }
  } else {
    for (int t = 0; t < TT; ++t) {
#pragma unroll
      for (int h = 0; h < 2; ++h) {
        const int rowbase = h * 64 + wv * 16;
        const int row = rowbase + r;
        cwait2(CPTR(3,h,0), CPTR(3,h,1), 32 * t, tid, lane);  // h0(t-1) fully written
        f32x4v accL[1];
        { f32x4v z = {0,0,0,0}; accL[0] = z; }
        if (gw) gemm_burst<1>(sm, h0b, rowbase, lane, accL);
        // linR in column halves as h2 arrives
        f32x4v accR[1];
        { f32x4v z = {0,0,0,0}; accR[0] = z; }
        cwait1(CPTR(2,h,0), 32 * (t + 1), tid);
        if (gw) gemm_half<1>(sm + 32768, h2b, rowbase, lane, 0, accR);
        cwait1(CPTR(2,h,1), 32 * (t + 1), tid);
        f32x4v o;
        if (gw) {
          gemm_half<1>(sm + 32768, h2b, rowbase, lane, 16, accR);
#pragma unroll
          for (int gg = 0; gg < 4; ++gg)
            o[gg] = ftanh(accL[0][gg] + accR[0][gg]);
          ucst64(h0b + (size_t)row * 1024 + c0 + q * 4, o);
        }
        SIGC(3, h);
        // out store AFTER the signal: off the h0 critical path (drains at the
        // next wait's barrier instead of before this signal).
        if (gw)
          *(f32x4v*)(out + ((size_t)row * 128 + t) * 1024 + c0 + q * 4) = o;
      }
    }
  }
}

// ------------------------- gi0 precompute -> gi0b[t][b][3H] bf16 -------------------------
// Grid: 48 n-tiles x 32 mi-groups. (r4 layout, unchanged.)
__global__ void __launch_bounds__(256) gi0_kernel(const float* __restrict__ X,
                                                  const __bf16* __restrict__ Wih0b,
                                                  __bf16* __restrict__ gi0b) {
  __shared__ char sm[131072];
  const int tid = threadIdx.x, wv = tid >> 6, lane = tid & 63;
  const int bi = blockIdx.x;
  const int n = bi % 48, mg = bi / 48;
#pragma unroll
  for (int s = 0; s < 4; ++s)
    stage_strip_b16(sm + s * 32768, Wih0b + (size_t)(n * 64 + s * 16) * 1024, tid);
  __syncthreads();
  const int r = lane & 15, q = lane >> 4;
  for (int mi = mg * 4; mi < mg * 4 + 4; ++mi) {
    f32x4v acc[4][2];
#pragma unroll
    for (int s = 0; s < 4; ++s) { f32x4v z = {0,0,0,0}; acc[s][0] = z; acc[s][1] = z; }
    const float* Ap = X + ((size_t)mi * 128 + wv * 32 + r) * 1024 + q * 8;
#pragma unroll 4
    for (int kb = 0; kb < 32; ++kb) {
      f32x4v x0a = *(const f32x4v*)(Ap + kb * 32);
      f32x4v x0b = *(const f32x4v*)(Ap + kb * 32 + 4);
      f32x4v x1a = *(const f32x4v*)(Ap + 16384 + kb * 32);
      f32x4v x1b = *(const f32x4v*)(Ap + 16384 + kb * 32 + 4);
      bf16x8 a0, a1;
#pragma unroll
      for (int j = 0; j < 4; ++j) {
        a0[j] = (__bf16)x0a[j]; a0[4 + j] = (__bf16)x0b[j];
        a1[j] = (__bf16)x1a[j]; a1[4 + j] = (__bf16)x1b[j];
      }
      const int byteo = (kb * 64 + q * 16) ^ ((r & 7) << 4);
#pragma unroll
      for (int s = 0; s < 4; ++s) {
        bf16x8 b = *(const bf16x8*)(sm + s * 32768 + r * 2048 + byteo);
        acc[s][0] = MFMA16(a0, b, acc[s][0]);
        acc[s][1] = MFMA16(a1, b, acc[s][1]);
      }
    }
#pragma unroll
    for (int s = 0; s < 4; ++s)
#pragma unroll
      for (int mf = 0; mf < 2; ++mf)
#pragma unroll
        for (int gg = 0; gg < 4; ++gg) {
          int trow = wv * 32 + mf * 16 + q * 4 + gg;     // = t
          gi0b[((size_t)trow * 128 + mi) * 3072 + n * 64 + s * 16 + r] = (__bf16)acc[s][mf][gg];
        }
  }
}

// ------------------------- prep: Wih0->bf16, state init, flags -------------------------
__global__ void __launch_bounds__(256) prep3(const float* __restrict__ Wih0f,
                                             const float* __restrict__ G,
                                             __bf16* Wih0b,
                                             __bf16* h0b, __bf16* h2b, int* flags) {
  long c = (long)blockIdx.x * 256 + threadIdx.x;
  if (c < 786432) {
    f32x4v v = *(const f32x4v*)(Wih0f + c * 4);
    bf16x4 o;
#pragma unroll
    for (int j = 0; j < 4; ++j) o[j] = (__bf16)v[j];
    *(bf16x4*)(Wih0b + c * 4) = o;
  } else if (c < 786432 + 131072) {
    long i = c - 786432;
    h0b[i] = (__bf16)G[i];
  } else if (c < 786432 + 262144) {
    long i = c - 786432 - 131072;
    h2b[i] = (__bf16)G[131072 + i];
  } else if (c < 786432 + 262144 + 8192) {
    flags[c - 786432 - 262144] = 0;
  }
}

// ------------------------- final LayerNorm (ddof=1, denom std+eps) -------------------------
__global__ void __launch_bounds__(256) ln_kernel(float* __restrict__ out,
                                                 const float* __restrict__ a2,
                                                 const float* __restrict__ b2) {
  int wv = threadIdx.x >> 6, lane = threadIdx.x & 63;
  size_t row = (size_t)blockIdx.x * 4 + wv;
  float* p = out + row * 1024;
  f32x4v v[4];
  float s = 0.f, ss = 0.f;
#pragma unroll
  for (int i = 0; i < 4; ++i) {
    v[i] = *(const f32x4v*)(p + (i * 64 + lane) * 4);
#pragma unroll
    for (int j = 0; j < 4; ++j) { s += v[i][j]; ss += v[i][j] * v[i][j]; }
  }
#pragma unroll
  for (int o = 32; o > 0; o >>= 1) { s += __shfl_xor(s, o); ss += __shfl_xor(ss, o); }
  float mean = s * (1.f / 1024.f);
  float var = (ss - 1024.f * mean * mean) * (1.f / 1023.f);
  var = fmaxf(var, 0.f);
  float inv = 1.f / (sqrtf(var) + 1e-6f);
#pragma unroll
  for (int i = 0; i < 4; ++i) {
    int c0 = (i * 64 + lane) * 4;
    f32x4v gA = *(const f32x4v*)(a2 + c0);
    f32x4v bo = *(const f32x4v*)(b2 + c0);
    f32x4v o;
#pragma unroll
    for (int j = 0; j < 4; ++j) o[j] = gA[j] * (v[i][j] - mean) * inv + bo[j];
    *(f32x4v*)(p + c0) = o;
  }
}

extern "C" void kernel_launch(void* const* d_in, const int* in_sizes, int n_in,
                              void* d_out, int out_size, void* d_ws, size_t ws_size,
                              hipStream_t stream) {
  const float* X    = (const float*)d_in[0];
  const float* G    = (const float*)d_in[1];
  // d_in[2] = L : dead (attention result discarded in reference)
  const float* Wih0 = (const float*)d_in[3];
  const float* Whh0 = (const float*)d_in[4];
  const float* Wih1 = (const float*)d_in[5];
  const float* Whh1 = (const float*)d_in[6];
  const float* Wlin = (const float*)d_in[7];
  const float* a2   = (const float*)d_in[8];
  const float* b2   = (const float*)d_in[9];
  float* out = (float*)d_out;

  char* ws = (char*)d_ws;
  size_t off = 0;
  auto take = [&](size_t n) { char* p = ws + off; off += (n + 255) & ~(size_t)255; return p; };
  __bf16* Wih0b = (__bf16*)take((size_t)3072 * 1024 * 2);
  __bf16* gi0b  = (__bf16*)take((size_t)16384 * 3072 * 2);   // 96 MB, [t][b][3H]
  __bf16* gh1b  = (__bf16*)take((size_t)64 * 3 * 128 * 16 * 2);  // strip-blocked
  __bf16* h0b   = (__bf16*)take((size_t)BB * HH * 2);        // row-major
  __bf16* h1b   = (__bf16*)take((size_t)BB * HH * 2 * 2);    // parity dbuf, strip-blocked
  __bf16* h2b   = (__bf16*)take((size_t)BB * HH * 2);        // row-major
  int*    flags = (int*)take(8192 * 4);                      // 16 counters, 64B/line
  if (off > ws_size) return; // workspace too small: fail loudly (output stays poisoned)

  prep3<<<4128, 256, 0, stream>>>(Wih0, G, Wih0b, h0b, h2b, flags);
  gi0_kernel<<<1536, 256, 0, stream>>>(X, Wih0b, gi0b);
  gru_persist<<<NWG, NT, 0, stream>>>(Whh0, Wih1, Whh1, Wlin, gi0b, G,
                                      h0b, h1b, h2b, gh1b, out, flags);
  ln_kernel<<<4096, 256, 0, stream>>>(out, a2, b2);
}

// Round 10
// 3612.157 us; speedup vs baseline: 1.2361x; 1.0880x over previous
//
#include <hip/hip_runtime.h>
#include <hip/hip_bf16.h>

#define BB 128
#define TT 128
#define HH 1024
#define NWG 256
#define NT 512

typedef __bf16 bf16x8 __attribute__((ext_vector_type(8)));
typedef __bf16 bf16x4 __attribute__((ext_vector_type(4)));
typedef float  f32x4v __attribute__((ext_vector_type(4)));

#define MFMA16(a,b,c) __builtin_amdgcn_mfma_f32_16x16x32_bf16(a,b,c,0,0,0)

__device__ inline float fsig(float x) {
  x = fminf(fmaxf(x, -30.f), 30.f);
  return 1.f / (1.f + __expf(-x));
}
__device__ inline float ftanh(float x) {
  x = fminf(fmaxf(x, -15.f), 15.f);
  float e = __expf(2.f * x);
  return (e - 1.f) / (e + 1.f);
}
// UC (LLC coherent-point) 8B store for cross-WG state: 4 consecutive bf16
__device__ inline void ucst64(__bf16* p, const f32x4v v) {
  union { unsigned long long u; __bf16 b[4]; } c;
#pragma unroll
  for (int j = 0; j < 4; ++j) c.b[j] = (__bf16)v[j];
  __hip_atomic_store((unsigned long long*)p, c.u, __ATOMIC_RELAXED, __HIP_MEMORY_SCOPE_AGENT);
}

// ---- DAG sync: aggregate monotone counters (r4 mechanism). One counter per
// (role, batch-half, column-half), each on its own 64B line.
#define CPTR(role,bh,ch) (flags + (((role)*2+(bh))*2+(ch))*16)

#define SIGC(role,bh) do { \
  __syncthreads(); \
  if (tid == 0) \
    __hip_atomic_fetch_add(CPTR(role,bh,chg), 1, __ATOMIC_RELAXED, __HIP_MEMORY_SCOPE_AGENT); \
} while (0)

__device__ inline void cwait1(const int* C, int tgt, int tid) {
  if (tid < 64) {
    while (__hip_atomic_load(C, __ATOMIC_RELAXED, __HIP_MEMORY_SCOPE_AGENT) < tgt)
      __builtin_amdgcn_s_sleep(1);
    __builtin_amdgcn_fence(__ATOMIC_ACQUIRE, "agent");
  }
  __syncthreads();
  __builtin_amdgcn_sched_barrier(0);
}
__device__ inline void cwait2(const int* C0, const int* C1, int tgt, int tid, int lane) {
  if (tid < 64) {
    const int* P = (lane < 32) ? C0 : C1;
    while (__hip_atomic_load(P, __ATOMIC_RELAXED, __HIP_MEMORY_SCOPE_AGENT) < tgt)
      __builtin_amdgcn_s_sleep(1);
    __builtin_amdgcn_fence(__ATOMIC_ACQUIRE, "agent");
  }
  __syncthreads();
  __builtin_amdgcn_sched_barrier(0);
}

// ---- stage one 16x1024 f32 weight strip into LDS as swizzled bf16 (32KB), NT=512 ----
__device__ inline void stage_strip(char* dst, const float* src, int rstride, int tid) {
#pragma unroll
  for (int it = 0; it < 8; ++it) {
    int i = tid + it * NT;
    int rr = i >> 8;
    int c4 = i & 255;
    f32x4v v = *(const f32x4v*)(src + (size_t)rr * rstride + c4 * 4);
    bf16x4 o;
#pragma unroll
    for (int j = 0; j < 4; ++j) o[j] = (__bf16)v[j];
    *(bf16x4*)(dst + rr * 2048 + ((c4 * 8) ^ ((rr & 7) << 4))) = o;
  }
}

// ---- stage one 16x1024 bf16 strip into LDS swizzled (32KB), 256 threads ----
__device__ inline void stage_strip_b16(char* dst, const __bf16* src, int tid) {
#pragma unroll
  for (int it = 0; it < 8; ++it) {
    int i = tid + it * 256;
    int rr = i >> 7;
    int c8 = i & 127;
    bf16x8 v = *(const bf16x8*)(src + (size_t)rr * 1024 + c8 * 8);
    *(bf16x8*)(dst + rr * 2048 + ((c8 * 16) ^ ((rr & 7) << 4))) = v;
  }
}

// ---- half-K GEMM burst (row-major A), transposed MFMA: D' = W x state^T ----
template<int NS>
__device__ inline void gemm_half(const char* sm, const __bf16* __restrict__ A,
                                 int rowbase, int lane, int kb0, f32x4v (&acc)[NS]) {
  const int r = lane & 15, q = lane >> 4;
  const __bf16* Ap = A + (size_t)(rowbase + r) * 1024 + q * 8;
  bf16x8 a[16];
#pragma unroll
  for (int i = 0; i < 16; ++i) a[i] = *(const bf16x8*)(Ap + (kb0 + i) * 32);
  __builtin_amdgcn_sched_barrier(0);   // pin: all 16 loads issued before MFMAs
  __builtin_amdgcn_s_setprio(1);
#pragma unroll
  for (int i = 0; i < 16; ++i) {
    const int kb = kb0 + i;
    const int byteo = (kb * 64 + q * 16) ^ ((r & 7) << 4);
#pragma unroll
    for (int s = 0; s < NS; ++s) {
      bf16x8 b = *(const bf16x8*)(sm + s * 32768 + r * 2048 + byteo);
      acc[s] = MFMA16(b, a[i], acc[s]);   // weights as A-operand (transposed D)
    }
  }
  __builtin_amdgcn_s_setprio(0);
}

// ---- half-K GEMM burst, STRIP-BLOCKED A ([64 strips][128 rows][16 cols]) ----
// k = kb*32 + q*8 + j  ->  strip 2*kb + (q>>1), cc = (q&1)*8 + j.
template<int NS>
__device__ inline void gemm_half_sb(const char* sm, const __bf16* __restrict__ A,
                                    int rowbase, int lane, int kb0, f32x4v (&acc)[NS]) {
  const int r = lane & 15, q = lane >> 4;
  const __bf16* Ap = A + ((size_t)(q >> 1) * 128 + (rowbase + r)) * 16 + (q & 1) * 8;
  bf16x8 a[16];
#pragma unroll
  for (int i = 0; i < 16; ++i) a[i] = *(const bf16x8*)(Ap + (size_t)(kb0 + i) * 4096);
  __builtin_amdgcn_sched_barrier(0);
  __builtin_amdgcn_s_setprio(1);
#pragma unroll
  for (int i = 0; i < 16; ++i) {
    const int kb = kb0 + i;
    const int byteo = (kb * 64 + q * 16) ^ ((r & 7) << 4);
#pragma unroll
    for (int s = 0; s < NS; ++s) {
      bf16x8 b = *(const bf16x8*)(sm + s * 32768 + r * 2048 + byteo);
      acc[s] = MFMA16(b, a[i], acc[s]);
    }
  }
  __builtin_amdgcn_s_setprio(0);
}

// ---- full-K GEMM burst (32 chunks, row-major A), transposed ----
template<int NS>
__device__ inline void gemm_burst(const char* sm, const __bf16* __restrict__ A,
                                  int rowbase, int lane, f32x4v (&acc)[NS]) {
  const int r = lane & 15, q = lane >> 4;
  const __bf16* Ap = A + (size_t)(rowbase + r) * 1024 + q * 8;
  bf16x8 a[32];
#pragma unroll
  for (int kb = 0; kb < 32; ++kb) a[kb] = *(const bf16x8*)(Ap + kb * 32);
  __builtin_amdgcn_sched_barrier(0);
  __builtin_amdgcn_s_setprio(1);
#pragma unroll
  for (int kb = 0; kb < 32; ++kb) {
    const int byteo = (kb * 64 + q * 16) ^ ((r & 7) << 4);
#pragma unroll
    for (int s = 0; s < NS; ++s) {
      bf16x8 b = *(const bf16x8*)(sm + s * 32768 + r * 2048 + byteo);
      acc[s] = MFMA16(b, a[kb], acc[s]);
    }
  }
  __builtin_amdgcn_s_setprio(0);
}

// ------------------------- persistent recurrent kernel (r6, byte-identical) ----
// XCD-affine roles: xcd = wg&7, role = xcd>>1. Two batch halves pipeline through
// the roles phase-shifted. Transposed-MFMA epilogue: lane holds
// row = rowbase + (lane&15), cols = c0 + (lane>>4)*4 + 0..3.
// h1b strip-blocked [64][128][16]; h0b/h2b/gh1b row-major (r7/r8/r9 lessons).
__global__ void __launch_bounds__(NT, 2) gru_persist(
    const float* __restrict__ Whh0, const float* __restrict__ Wih1,
    const float* __restrict__ Whh1, const float* __restrict__ Wlin,
    const __bf16* __restrict__ gi0b, const float* __restrict__ G,
    __bf16* __restrict__ h0b, __bf16* __restrict__ h1b,
    __bf16* __restrict__ h2b, __bf16* __restrict__ gh1b,
    float* __restrict__ out, int* flags)
{
  __shared__ char sm[107008];
  float* h2s = (float*)(sm + 98304);          // [128][17] f32 (pad 17), role 2
  const int tid = threadIdx.x, wg = blockIdx.x;
  const int wv = tid >> 6, lane = tid & 63;
  const int xcd = wg & 7;
  const int role = xcd >> 1;
  const int g = ((wg >> 3) << 1) | (xcd & 1); // 0..63
  const int c0 = g * 16;
  const int chg = (g >= 32);                  // my column half
  const int r = lane & 15, q = lane >> 4;
  const bool gw = (wv < 4);                   // GEMM waves (4 x 16 rows = 64-row half)

  if (role == 0) {
    stage_strip(sm,         Whh0 + (size_t)c0 * 1024,          1024, tid);
    stage_strip(sm + 32768, Whh0 + (size_t)(1024 + c0) * 1024, 1024, tid);
    stage_strip(sm + 65536, Whh0 + (size_t)(2048 + c0) * 1024, 1024, tid);
  } else if (role == 1) {
    stage_strip(sm,         Whh1 + (size_t)c0 * 1024,          1024, tid);
    stage_strip(sm + 32768, Whh1 + (size_t)(1024 + c0) * 1024, 1024, tid);
    stage_strip(sm + 65536, Whh1 + (size_t)(2048 + c0) * 1024, 1024, tid);
  } else if (role == 2) {
    stage_strip(sm,         Wih1 + (size_t)c0 * 1024,          1024, tid);
    stage_strip(sm + 32768, Wih1 + (size_t)(1024 + c0) * 1024, 1024, tid);
    stage_strip(sm + 65536, Wih1 + (size_t)(2048 + c0) * 1024, 1024, tid);
    for (int i = tid; i < 2048; i += NT) {    // h2 f32 master <- G[1] slice (all rows)
      int row = i >> 4, cc = i & 15;
      h2s[row * 17 + cc] = G[131072 + row * 1024 + c0 + cc];
    }
  } else {
    stage_strip(sm,         Wlin + (size_t)c0 * 2048,        2048, tid); // linL
    stage_strip(sm + 32768, Wlin + (size_t)c0 * 2048 + 1024, 2048, tid); // linR
  }
  __syncthreads();

  if (role == 0) {
    for (int t = 0; t < TT; ++t) {
      __bf16* h1bP = h1b + (size_t)(t & 1) * 131072;   // parity buffer
#pragma unroll
      for (int h = 0; h < 2; ++h) {
        const int rowbase = h * 64 + wv * 16;
        const int row = rowbase + r;
        // gi0 vectors: flag-independent — issue before waits to hide LLC latency
        bf16x4 vgr, vgz, vgn;
        if (gw) {
          const __bf16* gp = gi0b + ((size_t)t * 128 + row) * 3072 + c0 + q * 4;
          vgr = *(const bf16x4*)(gp);
          vgz = *(const bf16x4*)(gp + 1024);
          vgn = *(const bf16x4*)(gp + 2048);
        }
        f32x4v acc[3];
#pragma unroll
        for (int s = 0; s < 3; ++s) { f32x4v z = {0,0,0,0}; acc[s] = z; }
        cwait1(CPTR(3,h,0), 32 * t, tid);          // h0 cols 0..511 ready
        if (gw) gemm_half<3>(sm, h0b, rowbase, lane, 0, acc);
        cwait1(CPTR(3,h,1), 32 * t, tid);          // h0 cols 512..1023 ready
        if (gw) {
          bf16x4 vph = *(const bf16x4*)(h0b + (size_t)row * 1024 + c0 + q * 4);
          gemm_half<3>(sm, h0b, rowbase, lane, 16, acc);
          f32x4v o;
#pragma unroll
          for (int gg = 0; gg < 4; ++gg) {
            float rv = fsig((float)vgr[gg] + acc[0][gg]);
            float zv = fsig((float)vgz[gg] + acc[1][gg]);
            float nv = ftanh((float)vgn[gg] + rv * acc[2][gg]);
            o[gg] = (1.f - zv) * nv + zv * (float)vph[gg];
          }
          // strip-blocked h1: dense 2KB block per WG per phase
          ucst64(h1bP + ((size_t)g * 128 + row) * 16 + q * 4, o);
        }
        SIGC(0, h);
      }
    }
  } else if (role == 1) {
    for (int t = 0; t < TT; ++t) {
#pragma unroll
      for (int h = 0; h < 2; ++h) {
        cwait2(CPTR(2,h,0), CPTR(2,h,1), 32 * t, tid, lane);  // h2(t-1) ready
        if (gw) {
          const int rowbase = h * 64 + wv * 16;
          const int row = rowbase + r;
          f32x4v acc[3];
#pragma unroll
          for (int s = 0; s < 3; ++s) { f32x4v z = {0,0,0,0}; acc[s] = z; }
          gemm_burst<3>(sm, h2b, rowbase, lane, acc);
          size_t base = (size_t)row * 3072 + c0 + q * 4;
          ucst64(gh1b + base,        acc[0]);
          ucst64(gh1b + base + 1024, acc[1]);
          ucst64(gh1b + base + 2048, acc[2]);
        }
        SIGC(1, h);
      }
    }
  } else if (role == 2) {
    for (int t = 0; t < TT; ++t) {
      const __bf16* h1bP = h1b + (size_t)(t & 1) * 131072;
#pragma unroll
      for (int h = 0; h < 2; ++h) {
        const int rowbase = h * 64 + wv * 16;
        const int row = rowbase + r;
        // stage A: gh1 ready (parallel with role0) -> prefetch vectors early.
        cwait2(CPTR(1,h,0), CPTR(1,h,1), 32 * (t + 1), tid, lane);
        bf16x4 vh0, vh1, vh2;
        if (gw) {
          const __bf16* hp = gh1b + (size_t)row * 3072 + c0 + q * 4;
          vh0 = *(const bf16x4*)(hp);
          vh1 = *(const bf16x4*)(hp + 1024);
          vh2 = *(const bf16x4*)(hp + 2048);
        }
        // stage B: h1 (strip-blocked) in column halves
        f32x4v acc[3];
#pragma unroll
        for (int s = 0; s < 3; ++s) { f32x4v z = {0,0,0,0}; acc[s] = z; }
        cwait1(CPTR(0,h,0), 32 * (t + 1), tid);
        if (gw) gemm_half_sb<3>(sm, h1bP, rowbase, lane, 0, acc);
        cwait1(CPTR(0,h,1), 32 * (t + 1), tid);
        if (gw) {
          gemm_half_sb<3>(sm, h1bP, rowbase, lane, 16, acc);
          f32x4v o;
#pragma unroll
          for (int gg = 0; gg < 4; ++gg) {
            float rv = fsig(acc[0][gg] + (float)vh0[gg]);
            float zv = fsig(acc[1][gg] + (float)vh1[gg]);
            float nv = ftanh(acc[2][gg] + rv * (float)vh2[gg]);
            float hp2 = h2s[row * 17 + q * 4 + gg];
            float h2 = (1.f - zv) * nv + zv * hp2;
            h2s[row * 17 + q * 4 + gg] = h2;
            o[gg] = h2;
          }
          ucst64(h2b + (size_t)row * 1024 + c0 + q * 4, o);
        }
        SIGC(2, h);
      }
    }
  } else {
    for (int t = 0; t < TT; ++t) {
#pragma unroll
      for (int h = 0; h < 2; ++h) {
        const int rowbase = h * 64 + wv * 16;
        const int row = rowbase + r;
        cwait2(CPTR(3,h,0), CPTR(3,h,1), 32 * t, tid, lane);  // h0(t-1) fully written
        f32x4v accL[1];
        { f32x4v z = {0,0,0,0}; accL[0] = z; }
        if (gw) gemm_burst<1>(sm, h0b, rowbase, lane, accL);
        // linR in column halves as h2 arrives
        f32x4v accR[1];
        { f32x4v z = {0,0,0,0}; accR[0] = z; }
        cwait1(CPTR(2,h,0), 32 * (t + 1), tid);
        if (gw) gemm_half<1>(sm + 32768, h2b, rowbase, lane, 0, accR);
        cwait1(CPTR(2,h,1), 32 * (t + 1), tid);
        if (gw) {
          gemm_half<1>(sm + 32768, h2b, rowbase, lane, 16, accR);
          f32x4v o;
#pragma unroll
          for (int gg = 0; gg < 4; ++gg)
            o[gg] = ftanh(accL[0][gg] + accR[0][gg]);
          ucst64(h0b + (size_t)row * 1024 + c0 + q * 4, o);
          *(f32x4v*)(out + ((size_t)row * 128 + t) * 1024 + c0 + q * 4) = o;
        }
        SIGC(3, h);
      }
    }
  }
}

// ------------------------- gi0 precompute -> gi0b[t][b][3H] bf16 -------------------------
// Grid: 48 n-tiles x 32 mi-groups. r10: A-operand loads from PRE-CONVERTED bf16
// Xb (no per-iteration f32 loads + cvts): per kb, 2 bf16x8 loads + 8 MFMA
// instead of 4 f32x4 loads + 32 v_cvt + 8 MFMA. Halves A-traffic, removes the
// VALU bottleneck. Output layout unchanged.
__global__ void __launch_bounds__(256) gi0_kernel(const __bf16* __restrict__ Xb,
                                                  const __bf16* __restrict__ Wih0b,
                                                  __bf16* __restrict__ gi0b) {
  __shared__ char sm[131072];
  const int tid = threadIdx.x, wv = tid >> 6, lane = tid & 63;
  const int bi = blockIdx.x;
  const int n = bi % 48, mg = bi / 48;
#pragma unroll
  for (int s = 0; s < 4; ++s)
    stage_strip_b16(sm + s * 32768, Wih0b + (size_t)(n * 64 + s * 16) * 1024, tid);
  __syncthreads();
  const int r = lane & 15, q = lane >> 4;
  for (int mi = mg * 4; mi < mg * 4 + 4; ++mi) {
    f32x4v acc[4][2];
#pragma unroll
    for (int s = 0; s < 4; ++s) { f32x4v z = {0,0,0,0}; acc[s][0] = z; acc[s][1] = z; }
    const __bf16* Ap = Xb + ((size_t)mi * 128 + wv * 32 + r) * 1024 + q * 8;
#pragma unroll 8
    for (int kb = 0; kb < 32; ++kb) {
      bf16x8 a0 = *(const bf16x8*)(Ap + kb * 32);
      bf16x8 a1 = *(const bf16x8*)(Ap + 16384 + kb * 32);
      const int byteo = (kb * 64 + q * 16) ^ ((r & 7) << 4);
#pragma unroll
      for (int s = 0; s < 4; ++s) {
        bf16x8 b = *(const bf16x8*)(sm + s * 32768 + r * 2048 + byteo);
        acc[s][0] = MFMA16(a0, b, acc[s][0]);
        acc[s][1] = MFMA16(a1, b, acc[s][1]);
      }
    }
#pragma unroll
    for (int s = 0; s < 4; ++s)
#pragma unroll
      for (int mf = 0; mf < 2; ++mf)
#pragma unroll
        for (int gg = 0; gg < 4; ++gg) {
          int trow = wv * 32 + mf * 16 + q * 4 + gg;     // = t
          gi0b[((size_t)trow * 128 + mi) * 3072 + n * 64 + s * 16 + r] = (__bf16)acc[s][mf][gg];
        }
  }
}

// ------------------------- prep: Wih0->bf16, X->bf16, state init, flags ----
__global__ void __launch_bounds__(256) prep3(const float* __restrict__ Wih0f,
                                             const float* __restrict__ X,
                                             const float* __restrict__ G,
                                             __bf16* Wih0b, __bf16* Xb,
                                             __bf16* h0b, __bf16* h2b, int* flags) {
  long c = (long)blockIdx.x * 256 + threadIdx.x;
  if (c < 786432) {
    f32x4v v = *(const f32x4v*)(Wih0f + c * 4);
    bf16x4 o;
#pragma unroll
    for (int j = 0; j < 4; ++j) o[j] = (__bf16)v[j];
    *(bf16x4*)(Wih0b + c * 4) = o;
  } else if (c < 786432 + 131072) {
    long i = c - 786432;
    h0b[i] = (__bf16)G[i];
  } else if (c < 786432 + 262144) {
    long i = c - 786432 - 131072;
    h2b[i] = (__bf16)G[131072 + i];
  } else if (c < 786432 + 262144 + 8192) {
    flags[c - 786432 - 262144] = 0;
  } else if (c < 786432 + 262144 + 8192 + 4194304) {
    long i = c - (786432 + 262144 + 8192);   // 16384*1024/4 f32x4 groups
    f32x4v v = *(const f32x4v*)(X + i * 4);
    bf16x4 o;
#pragma unroll
    for (int j = 0; j < 4; ++j) o[j] = (__bf16)v[j];
    *(bf16x4*)(Xb + i * 4) = o;
  }
}

// ------------------------- final LayerNorm (ddof=1, denom std+eps) -------------------------
__global__ void __launch_bounds__(256) ln_kernel(float* __restrict__ out,
                                                 const float* __restrict__ a2,
                                                 const float* __restrict__ b2) {
  int wv = threadIdx.x >> 6, lane = threadIdx.x & 63;
  size_t row = (size_t)blockIdx.x * 4 + wv;
  float* p = out + row * 1024;
  f32x4v v[4];
  float s = 0.f, ss = 0.f;
#pragma unroll
  for (int i = 0; i < 4; ++i) {
    v[i] = *(const f32x4v*)(p + (i * 64 + lane) * 4);
#pragma unroll
    for (int j = 0; j < 4; ++j) { s += v[i][j]; ss += v[i][j] * v[i][j]; }
  }
#pragma unroll
  for (int o = 32; o > 0; o >>= 1) { s += __shfl_xor(s, o); ss += __shfl_xor(ss, o); }
  float mean = s * (1.f / 1024.f);
  float var = (ss - 1024.f * mean * mean) * (1.f / 1023.f);
  var = fmaxf(var, 0.f);
  float inv = 1.f / (sqrtf(var) + 1e-6f);
#pragma unroll
  for (int i = 0; i < 4; ++i) {
    int c0 = (i * 64 + lane) * 4;
    f32x4v gA = *(const f32x4v*)(a2 + c0);
    f32x4v bo = *(const f32x4v*)(b2 + c0);
    f32x4v o;
#pragma unroll
    for (int j = 0; j < 4; ++j) o[j] = gA[j] * (v[i][j] - mean) * inv + bo[j];
    *(f32x4v*)(p + c0) = o;
  }
}

extern "C" void kernel_launch(void* const* d_in, const int* in_sizes, int n_in,
                              void* d_out, int out_size, void* d_ws, size_t ws_size,
                              hipStream_t stream) {
  const float* X    = (const float*)d_in[0];
  const float* G    = (const float*)d_in[1];
  // d_in[2] = L : dead (attention result discarded in reference)
  const float* Wih0 = (const float*)d_in[3];
  const float* Whh0 = (const float*)d_in[4];
  const float* Wih1 = (const float*)d_in[5];
  const float* Whh1 = (const float*)d_in[6];
  const float* Wlin = (const float*)d_in[7];
  const float* a2   = (const float*)d_in[8];
  const float* b2   = (const float*)d_in[9];
  float* out = (float*)d_out;

  char* ws = (char*)d_ws;
  size_t off = 0;
  auto take = [&](size_t n) { char* p = ws + off; off += (n + 255) & ~(size_t)255; return p; };
  __bf16* Wih0b = (__bf16*)take((size_t)3072 * 1024 * 2);
  __bf16* Xb    = (__bf16*)take((size_t)16384 * 1024 * 2);   // 32 MB, X as bf16
  __bf16* gi0b  = (__bf16*)take((size_t)16384 * 3072 * 2);   // 96 MB, [t][b][3H]
  __bf16* gh1b  = (__bf16*)take((size_t)128 * 3072 * 2);
  __bf16* h0b   = (__bf16*)take((size_t)BB * HH * 2);        // row-major
  __bf16* h1b   = (__bf16*)take((size_t)BB * HH * 2 * 2);    // parity dbuf, strip-blocked
  __bf16* h2b   = (__bf16*)take((size_t)BB * HH * 2);        // row-major
  int*    flags = (int*)take(8192 * 4);                      // 16 counters, 64B/line
  if (off > ws_size) return; // workspace too small: fail loudly (output stays poisoned)

  prep3<<<20512, 256, 0, stream>>>(Wih0, X, G, Wih0b, Xb, h0b, h2b, flags);
  gi0_kernel<<<1536, 256, 0, stream>>>(Xb, Wih0b, gi0b);
  gru_persist<<<NWG, NT, 0, stream>>>(Whh0, Wih1, Whh1, Wlin, gi0b, G,
                                      h0b, h1b, h2b, gh1b, out, flags);
  ln_kernel<<<4096, 256, 0, stream>>>(out, a2, b2);
}

// Round 11
// 3540.405 us; speedup vs baseline: 1.2612x; 1.0203x over previous
//
#include <hip/hip_runtime.h>
#include <hip/hip_bf16.h>

#define BB 128
#define TT 128
#define HH 1024
#define NWG 256
#define NT 512

typedef __bf16 bf16x8 __attribute__((ext_vector_type(8)));
typedef __bf16 bf16x4 __attribute__((ext_vector_type(4)));
typedef float  f32x4v __attribute__((ext_vector_type(4)));

#define MFMA16(a,b,c) __builtin_amdgcn_mfma_f32_16x16x32_bf16(a,b,c,0,0,0)

__device__ inline float fsig(float x) {
  x = fminf(fmaxf(x, -30.f), 30.f);
  return 1.f / (1.f + __expf(-x));
}
__device__ inline float ftanh(float x) {
  x = fminf(fmaxf(x, -15.f), 15.f);
  float e = __expf(2.f * x);
  return (e - 1.f) / (e + 1.f);
}
// UC (LLC coherent-point) 8B store for cross-WG state: 4 consecutive bf16
__device__ inline void ucst64(__bf16* p, const f32x4v v) {
  union { unsigned long long u; __bf16 b[4]; } c;
#pragma unroll
  for (int j = 0; j < 4; ++j) c.b[j] = (__bf16)v[j];
  __hip_atomic_store((unsigned long long*)p, c.u, __ATOMIC_RELAXED, __HIP_MEMORY_SCOPE_AGENT);
}

// ---- DAG sync: aggregate monotone counters (r4 mechanism). One counter per
// (role, batch-half, column-half), each on its own 64B line.
#define CPTR(role,bh,ch) (flags + (((role)*2+(bh))*2+(ch))*16)

#define SIGC(role,bh) do { \
  __syncthreads(); \
  if (tid == 0) \
    __hip_atomic_fetch_add(CPTR(role,bh,chg), 1, __ATOMIC_RELAXED, __HIP_MEMORY_SCOPE_AGENT); \
} while (0)

__device__ inline void cwait1(const int* C, int tgt, int tid) {
  if (tid < 64) {
    while (__hip_atomic_load(C, __ATOMIC_RELAXED, __HIP_MEMORY_SCOPE_AGENT) < tgt)
      __builtin_amdgcn_s_sleep(1);
    __builtin_amdgcn_fence(__ATOMIC_ACQUIRE, "agent");
  }
  __syncthreads();
  __builtin_amdgcn_sched_barrier(0);
}
__device__ inline void cwait2(const int* C0, const int* C1, int tgt, int tid, int lane) {
  if (tid < 64) {
    const int* P = (lane < 32) ? C0 : C1;
    while (__hip_atomic_load(P, __ATOMIC_RELAXED, __HIP_MEMORY_SCOPE_AGENT) < tgt)
      __builtin_amdgcn_s_sleep(1);
    __builtin_amdgcn_fence(__ATOMIC_ACQUIRE, "agent");
  }
  __syncthreads();
  __builtin_amdgcn_sched_barrier(0);
}

// ---- stage one 16x1024 f32 weight strip into LDS as swizzled bf16 (32KB), NT=512 ----
__device__ inline void stage_strip(char* dst, const float* src, int rstride, int tid) {
#pragma unroll
  for (int it = 0; it < 8; ++it) {
    int i = tid + it * NT;
    int rr = i >> 8;
    int c4 = i & 255;
    f32x4v v = *(const f32x4v*)(src + (size_t)rr * rstride + c4 * 4);
    bf16x4 o;
#pragma unroll
    for (int j = 0; j < 4; ++j) o[j] = (__bf16)v[j];
    *(bf16x4*)(dst + rr * 2048 + ((c4 * 8) ^ ((rr & 7) << 4))) = o;
  }
}

// ---- stage one 16x1024 bf16 strip into LDS swizzled (32KB), 256 threads ----
__device__ inline void stage_strip_b16(char* dst, const __bf16* src, int tid) {
#pragma unroll
  for (int it = 0; it < 8; ++it) {
    int i = tid + it * 256;
    int rr = i >> 7;
    int c8 = i & 127;
    bf16x8 v = *(const bf16x8*)(src + (size_t)rr * 1024 + c8 * 8);
    *(bf16x8*)(dst + rr * 2048 + ((c8 * 16) ^ ((rr & 7) << 4))) = v;
  }
}

// ---- half-K GEMM burst (row-major A), transposed MFMA: D' = W x state^T ----
template<int NS>
__device__ inline void gemm_half(const char* sm, const __bf16* __restrict__ A,
                                 int rowbase, int lane, int kb0, f32x4v (&acc)[NS]) {
  const int r = lane & 15, q = lane >> 4;
  const __bf16* Ap = A + (size_t)(rowbase + r) * 1024 + q * 8;
  bf16x8 a[16];
#pragma unroll
  for (int i = 0; i < 16; ++i) a[i] = *(const bf16x8*)(Ap + (kb0 + i) * 32);
  __builtin_amdgcn_sched_barrier(0);   // pin: all 16 loads issued before MFMAs
  __builtin_amdgcn_s_setprio(1);
#pragma unroll
  for (int i = 0; i < 16; ++i) {
    const int kb = kb0 + i;
    const int byteo = (kb * 64 + q * 16) ^ ((r & 7) << 4);
#pragma unroll
    for (int s = 0; s < NS; ++s) {
      bf16x8 b = *(const bf16x8*)(sm + s * 32768 + r * 2048 + byteo);
      acc[s] = MFMA16(b, a[i], acc[s]);   // weights as A-operand (transposed D)
    }
  }
  __builtin_amdgcn_s_setprio(0);
}

// ---- half-K GEMM burst, STRIP-BLOCKED A ([64 strips][128 rows][16 cols]) ----
// k = kb*32 + q*8 + j  ->  strip 2*kb + (q>>1), cc = (q&1)*8 + j.
template<int NS>
__device__ inline void gemm_half_sb(const char* sm, const __bf16* __restrict__ A,
                                    int rowbase, int lane, int kb0, f32x4v (&acc)[NS]) {
  const int r = lane & 15, q = lane >> 4;
  const __bf16* Ap = A + ((size_t)(q >> 1) * 128 + (rowbase + r)) * 16 + (q & 1) * 8;
  bf16x8 a[16];
#pragma unroll
  for (int i = 0; i < 16; ++i) a[i] = *(const bf16x8*)(Ap + (size_t)(kb0 + i) * 4096);
  __builtin_amdgcn_sched_barrier(0);
  __builtin_amdgcn_s_setprio(1);
#pragma unroll
  for (int i = 0; i < 16; ++i) {
    const int kb = kb0 + i;
    const int byteo = (kb * 64 + q * 16) ^ ((r & 7) << 4);
#pragma unroll
    for (int s = 0; s < NS; ++s) {
      bf16x8 b = *(const bf16x8*)(sm + s * 32768 + r * 2048 + byteo);
      acc[s] = MFMA16(b, a[i], acc[s]);
    }
  }
  __builtin_amdgcn_s_setprio(0);
}

// ---- full-K GEMM burst (32 chunks, row-major A), transposed ----
template<int NS>
__device__ inline void gemm_burst(const char* sm, const __bf16* __restrict__ A,
                                  int rowbase, int lane, f32x4v (&acc)[NS]) {
  const int r = lane & 15, q = lane >> 4;
  const __bf16* Ap = A + (size_t)(rowbase + r) * 1024 + q * 8;
  bf16x8 a[32];
#pragma unroll
  for (int kb = 0; kb < 32; ++kb) a[kb] = *(const bf16x8*)(Ap + kb * 32);
  __builtin_amdgcn_sched_barrier(0);
  __builtin_amdgcn_s_setprio(1);
#pragma unroll
  for (int kb = 0; kb < 32; ++kb) {
    const int byteo = (kb * 64 + q * 16) ^ ((r & 7) << 4);
#pragma unroll
    for (int s = 0; s < NS; ++s) {
      bf16x8 b = *(const bf16x8*)(sm + s * 32768 + r * 2048 + byteo);
      acc[s] = MFMA16(b, a[kb], acc[s]);
    }
  }
  __builtin_amdgcn_s_setprio(0);
}

// ------------------------- persistent recurrent kernel (r6, byte-identical) ----
// XCD-affine roles: xcd = wg&7, role = xcd>>1. Two batch halves pipeline through
// the roles phase-shifted. Transposed-MFMA epilogue: lane holds
// row = rowbase + (lane&15), cols = c0 + (lane>>4)*4 + 0..3.
// h1b strip-blocked [64][128][16]; h0b/h2b/gh1b row-major (r7/r8/r9 lessons).
__global__ void __launch_bounds__(NT, 2) gru_persist(
    const float* __restrict__ Whh0, const float* __restrict__ Wih1,
    const float* __restrict__ Whh1, const float* __restrict__ Wlin,
    const __bf16* __restrict__ gi0b, const float* __restrict__ G,
    __bf16* __restrict__ h0b, __bf16* __restrict__ h1b,
    __bf16* __restrict__ h2b, __bf16* __restrict__ gh1b,
    float* __restrict__ out, int* flags)
{
  __shared__ char sm[107008];
  float* h2s = (float*)(sm + 98304);          // [128][17] f32 (pad 17), role 2
  const int tid = threadIdx.x, wg = blockIdx.x;
  const int wv = tid >> 6, lane = tid & 63;
  const int xcd = wg & 7;
  const int role = xcd >> 1;
  const int g = ((wg >> 3) << 1) | (xcd & 1); // 0..63
  const int c0 = g * 16;
  const int chg = (g >= 32);                  // my column half
  const int r = lane & 15, q = lane >> 4;
  const bool gw = (wv < 4);                   // GEMM waves (4 x 16 rows = 64-row half)

  if (role == 0) {
    stage_strip(sm,         Whh0 + (size_t)c0 * 1024,          1024, tid);
    stage_strip(sm + 32768, Whh0 + (size_t)(1024 + c0) * 1024, 1024, tid);
    stage_strip(sm + 65536, Whh0 + (size_t)(2048 + c0) * 1024, 1024, tid);
  } else if (role == 1) {
    stage_strip(sm,         Whh1 + (size_t)c0 * 1024,          1024, tid);
    stage_strip(sm + 32768, Whh1 + (size_t)(1024 + c0) * 1024, 1024, tid);
    stage_strip(sm + 65536, Whh1 + (size_t)(2048 + c0) * 1024, 1024, tid);
  } else if (role == 2) {
    stage_strip(sm,         Wih1 + (size_t)c0 * 1024,          1024, tid);
    stage_strip(sm + 32768, Wih1 + (size_t)(1024 + c0) * 1024, 1024, tid);
    stage_strip(sm + 65536, Wih1 + (size_t)(2048 + c0) * 1024, 1024, tid);
    for (int i = tid; i < 2048; i += NT) {    // h2 f32 master <- G[1] slice (all rows)
      int row = i >> 4, cc = i & 15;
      h2s[row * 17 + cc] = G[131072 + row * 1024 + c0 + cc];
    }
  } else {
    stage_strip(sm,         Wlin + (size_t)c0 * 2048,        2048, tid); // linL
    stage_strip(sm + 32768, Wlin + (size_t)c0 * 2048 + 1024, 2048, tid); // linR
  }
  __syncthreads();

  if (role == 0) {
    for (int t = 0; t < TT; ++t) {
      __bf16* h1bP = h1b + (size_t)(t & 1) * 131072;   // parity buffer
#pragma unroll
      for (int h = 0; h < 2; ++h) {
        const int rowbase = h * 64 + wv * 16;
        const int row = rowbase + r;
        // gi0 vectors: flag-independent — issue before waits to hide LLC latency
        bf16x4 vgr, vgz, vgn;
        if (gw) {
          const __bf16* gp = gi0b + ((size_t)t * 128 + row) * 3072 + c0 + q * 4;
          vgr = *(const bf16x4*)(gp);
          vgz = *(const bf16x4*)(gp + 1024);
          vgn = *(const bf16x4*)(gp + 2048);
        }
        f32x4v acc[3];
#pragma unroll
        for (int s = 0; s < 3; ++s) { f32x4v z = {0,0,0,0}; acc[s] = z; }
        cwait1(CPTR(3,h,0), 32 * t, tid);          // h0 cols 0..511 ready
        if (gw) gemm_half<3>(sm, h0b, rowbase, lane, 0, acc);
        cwait1(CPTR(3,h,1), 32 * t, tid);          // h0 cols 512..1023 ready
        if (gw) {
          bf16x4 vph = *(const bf16x4*)(h0b + (size_t)row * 1024 + c0 + q * 4);
          gemm_half<3>(sm, h0b, rowbase, lane, 16, acc);
          f32x4v o;
#pragma unroll
          for (int gg = 0; gg < 4; ++gg) {
            float rv = fsig((float)vgr[gg] + acc[0][gg]);
            float zv = fsig((float)vgz[gg] + acc[1][gg]);
            float nv = ftanh((float)vgn[gg] + rv * acc[2][gg]);
            o[gg] = (1.f - zv) * nv + zv * (float)vph[gg];
          }
          // strip-blocked h1: dense 2KB block per WG per phase
          ucst64(h1bP + ((size_t)g * 128 + row) * 16 + q * 4, o);
        }
        SIGC(0, h);
      }
    }
  } else if (role == 1) {
    for (int t = 0; t < TT; ++t) {
#pragma unroll
      for (int h = 0; h < 2; ++h) {
        cwait2(CPTR(2,h,0), CPTR(2,h,1), 32 * t, tid, lane);  // h2(t-1) ready
        if (gw) {
          const int rowbase = h * 64 + wv * 16;
          const int row = rowbase + r;
          f32x4v acc[3];
#pragma unroll
          for (int s = 0; s < 3; ++s) { f32x4v z = {0,0,0,0}; acc[s] = z; }
          gemm_burst<3>(sm, h2b, rowbase, lane, acc);
          size_t base = (size_t)row * 3072 + c0 + q * 4;
          ucst64(gh1b + base,        acc[0]);
          ucst64(gh1b + base + 1024, acc[1]);
          ucst64(gh1b + base + 2048, acc[2]);
        }
        SIGC(1, h);
      }
    }
  } else if (role == 2) {
    for (int t = 0; t < TT; ++t) {
      const __bf16* h1bP = h1b + (size_t)(t & 1) * 131072;
#pragma unroll
      for (int h = 0; h < 2; ++h) {
        const int rowbase = h * 64 + wv * 16;
        const int row = rowbase + r;
        // stage A: gh1 ready (parallel with role0) -> prefetch vectors early.
        cwait2(CPTR(1,h,0), CPTR(1,h,1), 32 * (t + 1), tid, lane);
        bf16x4 vh0, vh1, vh2;
        if (gw) {
          const __bf16* hp = gh1b + (size_t)row * 3072 + c0 + q * 4;
          vh0 = *(const bf16x4*)(hp);
          vh1 = *(const bf16x4*)(hp + 1024);
          vh2 = *(const bf16x4*)(hp + 2048);
        }
        // stage B: h1 (strip-blocked) in column halves
        f32x4v acc[3];
#pragma unroll
        for (int s = 0; s < 3; ++s) { f32x4v z = {0,0,0,0}; acc[s] = z; }
        cwait1(CPTR(0,h,0), 32 * (t + 1), tid);
        if (gw) gemm_half_sb<3>(sm, h1bP, rowbase, lane, 0, acc);
        cwait1(CPTR(0,h,1), 32 * (t + 1), tid);
        if (gw) {
          gemm_half_sb<3>(sm, h1bP, rowbase, lane, 16, acc);
          f32x4v o;
#pragma unroll
          for (int gg = 0; gg < 4; ++gg) {
            float rv = fsig(acc[0][gg] + (float)vh0[gg]);
            float zv = fsig(acc[1][gg] + (float)vh1[gg]);
            float nv = ftanh(acc[2][gg] + rv * (float)vh2[gg]);
            float hp2 = h2s[row * 17 + q * 4 + gg];
            float h2 = (1.f - zv) * nv + zv * hp2;
            h2s[row * 17 + q * 4 + gg] = h2;
            o[gg] = h2;
          }
          ucst64(h2b + (size_t)row * 1024 + c0 + q * 4, o);
        }
        SIGC(2, h);
      }
    }
  } else {
    for (int t = 0; t < TT; ++t) {
#pragma unroll
      for (int h = 0; h < 2; ++h) {
        const int rowbase = h * 64 + wv * 16;
        const int row = rowbase + r;
        cwait2(CPTR(3,h,0), CPTR(3,h,1), 32 * t, tid, lane);  // h0(t-1) fully written
        f32x4v accL[1];
        { f32x4v z = {0,0,0,0}; accL[0] = z; }
        if (gw) gemm_burst<1>(sm, h0b, rowbase, lane, accL);
        // linR in column halves as h2 arrives
        f32x4v accR[1];
        { f32x4v z = {0,0,0,0}; accR[0] = z; }
        cwait1(CPTR(2,h,0), 32 * (t + 1), tid);
        if (gw) gemm_half<1>(sm + 32768, h2b, rowbase, lane, 0, accR);
        cwait1(CPTR(2,h,1), 32 * (t + 1), tid);
        if (gw) {
          gemm_half<1>(sm + 32768, h2b, rowbase, lane, 16, accR);
          f32x4v o;
#pragma unroll
          for (int gg = 0; gg < 4; ++gg)
            o[gg] = ftanh(accL[0][gg] + accR[0][gg]);
          ucst64(h0b + (size_t)row * 1024 + c0 + q * 4, o);
          *(f32x4v*)(out + ((size_t)row * 128 + t) * 1024 + c0 + q * 4) = o;
        }
        SIGC(3, h);
      }
    }
  }
}

// ------------------------- gi0 precompute -> gi0b[t][b][3H] bf16 -------------------------
// Grid: 48 n-tiles x 32 mi-groups. r11: the 4-mi loop is FUSED into the kb loop
// so each LDS B-fragment is reused across all 4 mi A-operands: per kb per wave,
// 4 ds_read_b128 : 32 MFMA (was 16 : 32 over the unfused iterations) -> LDS
// issue drops below the MFMA floor. acc[4][4][2]=128 VGPR + a[4][2]=32 is fine:
// 128KB LDS already caps at 1 block/CU, and launch_bounds(256,1) unlocks the
// register budget. All indices compile-time (full unroll).
__global__ void __launch_bounds__(256, 1) gi0_kernel(const __bf16* __restrict__ Xb,
                                                  const __bf16* __restrict__ Wih0b,
                                                  __bf16* __restrict__ gi0b) {
  __shared__ char sm[131072];
  const int tid = threadIdx.x, wv = tid >> 6, lane = tid & 63;
  const int bi = blockIdx.x;
  const int n = bi % 48, mg = bi / 48;
#pragma unroll
  for (int s = 0; s < 4; ++s)
    stage_strip_b16(sm + s * 32768, Wih0b + (size_t)(n * 64 + s * 16) * 1024, tid);
  __syncthreads();
  const int r = lane & 15, q = lane >> 4;
  f32x4v acc[4][4][2];   // [s][m][mf]
#pragma unroll
  for (int s = 0; s < 4; ++s)
#pragma unroll
    for (int m = 0; m < 4; ++m) {
      f32x4v z = {0,0,0,0};
      acc[s][m][0] = z; acc[s][m][1] = z;
    }
  const __bf16* Ap = Xb + (((size_t)mg * 4) * 128 + wv * 32 + r) * 1024 + q * 8;
#pragma unroll 2
  for (int kb = 0; kb < 32; ++kb) {
    bf16x8 a[4][2];
#pragma unroll
    for (int m = 0; m < 4; ++m) {
      a[m][0] = *(const bf16x8*)(Ap + (size_t)m * 131072 + kb * 32);
      a[m][1] = *(const bf16x8*)(Ap + (size_t)m * 131072 + 16384 + kb * 32);
    }
    const int byteo = (kb * 64 + q * 16) ^ ((r & 7) << 4);
#pragma unroll
    for (int s = 0; s < 4; ++s) {
      bf16x8 b = *(const bf16x8*)(sm + s * 32768 + r * 2048 + byteo);
#pragma unroll
      for (int m = 0; m < 4; ++m) {
        acc[s][m][0] = MFMA16(a[m][0], b, acc[s][m][0]);
        acc[s][m][1] = MFMA16(a[m][1], b, acc[s][m][1]);
      }
    }
  }
#pragma unroll
  for (int s = 0; s < 4; ++s)
#pragma unroll
    for (int m = 0; m < 4; ++m)
#pragma unroll
      for (int mf = 0; mf < 2; ++mf)
#pragma unroll
        for (int gg = 0; gg < 4; ++gg) {
          int trow = wv * 32 + mf * 16 + q * 4 + gg;     // = t
          int mi = mg * 4 + m;
          gi0b[((size_t)trow * 128 + mi) * 3072 + n * 64 + s * 16 + r] =
              (__bf16)acc[s][m][mf][gg];
        }
}

// ------------------------- prep: Wih0->bf16, X->bf16, state init, flags ----
__global__ void __launch_bounds__(256) prep3(const float* __restrict__ Wih0f,
                                             const float* __restrict__ X,
                                             const float* __restrict__ G,
                                             __bf16* Wih0b, __bf16* Xb,
                                             __bf16* h0b, __bf16* h2b, int* flags) {
  long c = (long)blockIdx.x * 256 + threadIdx.x;
  if (c < 786432) {
    f32x4v v = *(const f32x4v*)(Wih0f + c * 4);
    bf16x4 o;
#pragma unroll
    for (int j = 0; j < 4; ++j) o[j] = (__bf16)v[j];
    *(bf16x4*)(Wih0b + c * 4) = o;
  } else if (c < 786432 + 131072) {
    long i = c - 786432;
    h0b[i] = (__bf16)G[i];
  } else if (c < 786432 + 262144) {
    long i = c - 786432 - 131072;
    h2b[i] = (__bf16)G[131072 + i];
  } else if (c < 786432 + 262144 + 8192) {
    flags[c - 786432 - 262144] = 0;
  } else if (c < 786432 + 262144 + 8192 + 4194304) {
    long i = c - (786432 + 262144 + 8192);   // 16384*1024/4 f32x4 groups
    f32x4v v = *(const f32x4v*)(X + i * 4);
    bf16x4 o;
#pragma unroll
    for (int j = 0; j < 4; ++j) o[j] = (__bf16)v[j];
    *(bf16x4*)(Xb + i * 4) = o;
  }
}

// ------------------------- final LayerNorm (ddof=1, denom std+eps) -------------------------
__global__ void __launch_bounds__(256) ln_kernel(float* __restrict__ out,
                                                 const float* __restrict__ a2,
                                                 const float* __restrict__ b2) {
  int wv = threadIdx.x >> 6, lane = threadIdx.x & 63;
  size_t row = (size_t)blockIdx.x * 4 + wv;
  float* p = out + row * 1024;
  f32x4v v[4];
  float s = 0.f, ss = 0.f;
#pragma unroll
  for (int i = 0; i < 4; ++i) {
    v[i] = *(const f32x4v*)(p + (i * 64 + lane) * 4);
#pragma unroll
    for (int j = 0; j < 4; ++j) { s += v[i][j]; ss += v[i][j] * v[i][j]; }
  }
#pragma unroll
  for (int o = 32; o > 0; o >>= 1) { s += __shfl_xor(s, o); ss += __shfl_xor(ss, o); }
  float mean = s * (1.f / 1024.f);
  float var = (ss - 1024.f * mean * mean) * (1.f / 1023.f);
  var = fmaxf(var, 0.f);
  float inv = 1.f / (sqrtf(var) + 1e-6f);
#pragma unroll
  for (int i = 0; i < 4; ++i) {
    int c0 = (i * 64 + lane) * 4;
    f32x4v gA = *(const f32x4v*)(a2 + c0);
    f32x4v bo = *(const f32x4v*)(b2 + c0);
    f32x4v o;
#pragma unroll
    for (int j = 0; j < 4; ++j) o[j] = gA[j] * (v[i][j] - mean) * inv + bo[j];
    *(f32x4v*)(p + c0) = o;
  }
}

extern "C" void kernel_launch(void* const* d_in, const int* in_sizes, int n_in,
                              void* d_out, int out_size, void* d_ws, size_t ws_size,
                              hipStream_t stream) {
  const float* X    = (const float*)d_in[0];
  const float* G    = (const float*)d_in[1];
  // d_in[2] = L : dead (attention result discarded in reference)
  const float* Wih0 = (const float*)d_in[3];
  const float* Whh0 = (const float*)d_in[4];
  const float* Wih1 = (const float*)d_in[5];
  const float* Whh1 = (const float*)d_in[6];
  const float* Wlin = (const float*)d_in[7];
  const float* a2   = (const float*)d_in[8];
  const float* b2   = (const float*)d_in[9];
  float* out = (float*)d_out;

  char* ws = (char*)d_ws;
  size_t off = 0;
  auto take = [&](size_t n) { char* p = ws + off; off += (n + 255) & ~(size_t)255; return p; };
  __bf16* Wih0b = (__bf16*)take((size_t)3072 * 1024 * 2);
  __bf16* Xb    = (__bf16*)take((size_t)16384 * 1024 * 2);   // 32 MB, X as bf16
  __bf16* gi0b  = (__bf16*)take((size_t)16384 * 3072 * 2);   // 96 MB, [t][b][3H]
  __bf16* gh1b  = (__bf16*)take((size_t)128 * 3072 * 2);
  __bf16* h0b   = (__bf16*)take((size_t)BB * HH * 2);        // row-major
  __bf16* h1b   = (__bf16*)take((size_t)BB * HH * 2 * 2);    // parity dbuf, strip-blocked
  __bf16* h2b   = (__bf16*)take((size_t)BB * HH * 2);        // row-major
  int*    flags = (int*)take(8192 * 4);                      // 16 counters, 64B/line
  if (off > ws_size) return; // workspace too small: fail loudly (output stays poisoned)

  prep3<<<20512, 256, 0, stream>>>(Wih0, X, G, Wih0b, Xb, h0b, h2b, flags);
  gi0_kernel<<<1536, 256, 0, stream>>>(Xb, Wih0b, gi0b);
  gru_persist<<<NWG, NT, 0, stream>>>(Whh0, Wih1, Whh1, Wlin, gi0b, G,
                                      h0b, h1b, h2b, gh1b, out, flags);
  ln_kernel<<<4096, 256, 0, stream>>>(out, a2, b2);
}